// Round 1
// baseline (6830.708 us; speedup 1.0000x reference)
//
#include <hip/hip_runtime.h>
#include <math.h>

#define CC 512
#define NH 8
#define HD 64
#define NB 8
#define TT 256

// ---------------- LayerNorm: one block (256 thr) per row of 512 ----------------
__global__ __launch_bounds__(256) void ln_k(const float* __restrict__ in,
    float* __restrict__ out, const float* __restrict__ g, const float* __restrict__ b) {
  int row = blockIdx.x, t = threadIdx.x;
  const float* r = in + (size_t)row * CC;
  float v0 = r[t], v1 = r[t + 256];
  float s = v0 + v1;
  #pragma unroll
  for (int o = 32; o; o >>= 1) s += __shfl_xor(s, o);
  __shared__ float r1[4], r2[4];
  if ((t & 63) == 0) r1[t >> 6] = s;
  __syncthreads();
  float mu = (r1[0] + r1[1] + r1[2] + r1[3]) * (1.0f / CC);
  float d0 = v0 - mu, d1 = v1 - mu;
  float sq = d0 * d0 + d1 * d1;
  #pragma unroll
  for (int o = 32; o; o >>= 1) sq += __shfl_xor(sq, o);
  if ((t & 63) == 0) r2[t >> 6] = sq;
  __syncthreads();
  float var = (r2[0] + r2[1] + r2[2] + r2[3]) * (1.0f / CC);
  float inv = rsqrtf(var + 1e-5f);
  float* w = out + (size_t)row * CC;
  w[t]       = d0 * inv * g[t]       + b[t];
  w[t + 256] = d1 * inv * g[t + 256] + b[t + 256];
}

// ---------------- fp32 GEMM: out[M,N] = act(A[M,K] @ W[K,N] + bias) (+res) ----
template<int GELU, int RES>
__global__ __launch_bounds__(256) void gemm_k(const float* __restrict__ A,
    const float* __restrict__ W, const float* __restrict__ bias,
    float* __restrict__ out, const float* __restrict__ res,
    int M, int N, int K) {
  __shared__ float As[16][68];  // [k][m], pad keeps float4 alignment (68*4=272B)
  __shared__ float Bs[16][68];  // [k][n]
  int bm = blockIdx.y << 6, bn = blockIdx.x << 6;
  int tid = threadIdx.x;
  int tm = (tid >> 4) << 2, tn = (tid & 15) << 2;
  int ar = tid >> 2, ac = (tid & 3) << 2;
  int br = tid >> 4, bc = (tid & 15) << 2;
  const float* Ap = A + (size_t)(bm + ar) * K + ac;
  const float* Wp = W + (size_t)br * N + bn + bc;
  float acc[4][4] = {};
  for (int k0 = 0; k0 < K; k0 += 16) {
    float4 a4 = *(const float4*)(Ap + k0);
    As[ac + 0][ar] = a4.x; As[ac + 1][ar] = a4.y;
    As[ac + 2][ar] = a4.z; As[ac + 3][ar] = a4.w;
    *(float4*)&Bs[br][bc] = *(const float4*)(Wp + (size_t)k0 * N);
    __syncthreads();
    #pragma unroll
    for (int kk = 0; kk < 16; kk++) {
      float4 av = *(const float4*)&As[kk][tm];
      float4 bv = *(const float4*)&Bs[kk][tn];
      acc[0][0] += av.x * bv.x; acc[0][1] += av.x * bv.y; acc[0][2] += av.x * bv.z; acc[0][3] += av.x * bv.w;
      acc[1][0] += av.y * bv.x; acc[1][1] += av.y * bv.y; acc[1][2] += av.y * bv.z; acc[1][3] += av.y * bv.w;
      acc[2][0] += av.z * bv.x; acc[2][1] += av.z * bv.y; acc[2][2] += av.z * bv.z; acc[2][3] += av.z * bv.w;
      acc[3][0] += av.w * bv.x; acc[3][1] += av.w * bv.y; acc[3][2] += av.w * bv.z; acc[3][3] += av.w * bv.w;
    }
    __syncthreads();
  }
  #pragma unroll
  for (int i = 0; i < 4; i++) {
    int rr = bm + tm + i;
    #pragma unroll
    for (int j = 0; j < 4; j++) {
      int ccol = bn + tn + j;
      float vv = acc[i][j] + bias[ccol];
      if (GELU) vv = 0.5f * vv * (1.0f + erff(vv * 0.70710678118654752f));
      if (RES)  vv += res[(size_t)rr * N + ccol];
      out[(size_t)rr * N + ccol] = vv;
    }
  }
}

// ---------------- Attention: 1 wave per (b,h,query-row); 4 waves/block --------
// NT = Ts/64. TOPK: exact 64th-largest threshold via iterative wave-max extraction
// (keeps s >= thr, matching jnp.where(att < top[...,-1:], -inf, att) incl. ties).
template<int CAUSAL, int TOPK, int NT>
__global__ __launch_bounds__(256) void attn_k(const float* __restrict__ q,
    const float* __restrict__ k, const float* __restrict__ v, float* __restrict__ y) {
  const int Ts = NT * 64;
  int wid = threadIdx.x >> 6, lane = threadIdx.x & 63;
  int g = (blockIdx.x << 2) + wid;
  int b = g >> 11;            // / (NH*TT) = 2048
  int rem = g & 2047;
  int h = rem >> 8;           // / TT
  int qi = rem & 255;
  __shared__ float sw[4][NT * 64];
  __shared__ float qs[4][64];
  qs[wid][lane] = q[(size_t)(b * TT + qi) * CC + h * HD + lane];
  __syncthreads();
  int jmax = CAUSAL ? (qi + 1) : Ts;
  const float* kb = k + (size_t)b * Ts * CC + h * HD;
  float sc[NT];
  float lmax = -3.0e38f;
  #pragma unroll
  for (int t = 0; t < NT; t++) {
    int j = lane + (t << 6);
    float acc;
    if (j < jmax) {
      const float* kr = kb + (size_t)j * CC;
      acc = 0.f;
      #pragma unroll
      for (int d = 0; d < 64; d += 4) {
        float4 k4 = *(const float4*)(kr + d);
        acc += qs[wid][d] * k4.x + qs[wid][d + 1] * k4.y
             + qs[wid][d + 2] * k4.z + qs[wid][d + 3] * k4.w;
      }
      acc *= 0.125f;  // 1/sqrt(64)
    } else {
      acc = -3.0e38f;
    }
    sc[t] = acc;
    lmax = fmaxf(lmax, acc);
  }
  float mx = lmax;
  #pragma unroll
  for (int o = 32; o; o >>= 1) mx = fmaxf(mx, __shfl_xor(mx, o));
  float thr = -3.0e38f;
  if (TOPK) {
    float wc[NT];
    #pragma unroll
    for (int t = 0; t < NT; t++) wc[t] = sc[t];
    for (int it = 0; it < 64; it++) {
      float lm = -3.0e38f; int li = 0;
      #pragma unroll
      for (int t = 0; t < NT; t++) if (wc[t] > lm) { lm = wc[t]; li = t; }
      float wm = lm;
      #pragma unroll
      for (int o = 32; o; o >>= 1) wm = fmaxf(wm, __shfl_xor(wm, o));
      unsigned long long ball = __ballot(lm == wm);
      int src = __ffsll((long long)ball) - 1;  // remove exactly one instance
      if (lane == src) wc[li] = -3.0e38f;
      thr = wm;  // after 64 iters: 64th-largest (duplicates counted)
    }
  }
  float psum = 0.f;
  #pragma unroll
  for (int t = 0; t < NT; t++) {
    int j = lane + (t << 6);
    float wv = 0.f;
    if (j < jmax) {
      if (!TOPK || sc[t] >= thr) wv = expf(sc[t] - mx);
    }
    sw[wid][j] = wv;
    psum += wv;
  }
  #pragma unroll
  for (int o = 32; o; o >>= 1) psum += __shfl_xor(psum, o);
  __syncthreads();
  float inv = 1.0f / psum;
  const float* vb = v + (size_t)b * Ts * CC + h * HD + lane;
  float acc = 0.f;
  #pragma unroll 4
  for (int j = 0; j < jmax; j++) acc += sw[wid][j] * vb[(size_t)j * CC];
  y[(size_t)(b * TT + qi) * CC + h * HD + lane] = acc * inv;
}

extern "C" void kernel_launch(void* const* d_in, const int* in_sizes, int n_in,
                              void* d_out, int out_size, void* d_ws, size_t ws_size,
                              hipStream_t stream) {
  const float* id_x    = (const float*)d_in[0];
  const float* id_prev = (const float*)d_in[1];
  const float* frames  = (const float*)d_in[2];
  const float* Wq = (const float*)d_in[3];  const float* bq = (const float*)d_in[4];
  const float* Wk = (const float*)d_in[5];  const float* bk = (const float*)d_in[6];
  const float* Wv = (const float*)d_in[7];  const float* bv = (const float*)d_in[8];
  const float* Wo = (const float*)d_in[9];  const float* bo = (const float*)d_in[10];
  const float* W1 = (const float*)d_in[11]; const float* b1 = (const float*)d_in[12];
  const float* W2 = (const float*)d_in[13]; const float* b2 = (const float*)d_in[14];
  const float* l1g = (const float*)d_in[15]; const float* l1b = (const float*)d_in[16];
  const float* l2g = (const float*)d_in[17]; const float* l2b = (const float*)d_in[18];
  const float* lfg = (const float*)d_in[19]; const float* lfb = (const float*)d_in[20];

  float* x  = (float*)d_out;                 // running residual stream [2048,512]
  float* ws = (float*)d_ws;
  const size_t M1 = (size_t)2048 * 512;      // 1,048,576 floats
  float* h  = ws;                            // ln output / MLP hidden input
  float* q  = ws + M1;
  float* yb = ws + 2 * M1;                   // attention output
  float* kb = ws + 3 * M1;                   // K [<=4096,512]
  float* vb = ws + 5 * M1;                   // V [<=4096,512]
  float* m1 = ws + 3 * M1;                   // MLP intermediate [2048,2048], aliases k/v

  hipMemcpyAsync(x, id_x, M1 * sizeof(float), hipMemcpyDeviceToDevice, stream);

  static const int ssrc[10] = {0, 0, 0, 0, 1, 1, 2, 2, 1, 1};  // 0=frames,1=self,2=id_prev

  for (int i = 0; i < 10; i++) {
    const float* kv; int Nkv;
    if (ssrc[i] == 0)      { kv = frames;  Nkv = 4096; }
    else if (ssrc[i] == 1) { kv = x;       Nkv = 2048; }
    else                   { kv = id_prev; Nkv = 2048; }

    const size_t wo = (size_t)i * 512 * 512;
    const size_t w1o = (size_t)i * 512 * 2048;

    // h = LN1(x)
    ln_k<<<2048, 256, 0, stream>>>(x, h, l1g + i * 512, l1b + i * 512);
    // q = h @ Wq + bq
    gemm_k<0, 0><<<dim3(8, 32), 256, 0, stream>>>(h, Wq + wo, bq + i * 512, q, nullptr, 2048, 512, 512);
    // k,v = kv @ Wk/Wv + b   (kv is RAW x for self layers, per reference)
    gemm_k<0, 0><<<dim3(8, Nkv / 64), 256, 0, stream>>>(kv, Wk + wo, bk + i * 512, kb, nullptr, Nkv, 512, 512);
    gemm_k<0, 0><<<dim3(8, Nkv / 64), 256, 0, stream>>>(kv, Wv + wo, bv + i * 512, vb, nullptr, Nkv, 512, 512);
    // attention
    if (ssrc[i] == 0)      attn_k<0, 1, 8><<<4096, 256, 0, stream>>>(q, kb, vb, yb);
    else if (ssrc[i] == 1) attn_k<1, 0, 4><<<4096, 256, 0, stream>>>(q, kb, vb, yb);
    else                   attn_k<0, 0, 4><<<4096, 256, 0, stream>>>(q, kb, vb, yb);
    // x = x + y @ Wo + bo
    gemm_k<0, 1><<<dim3(8, 32), 256, 0, stream>>>(yb, Wo + wo, bo + i * 512, x, x, 2048, 512, 512);
    // h = LN2(x)
    ln_k<<<2048, 256, 0, stream>>>(x, h, l2g + i * 512, l2b + i * 512);
    // m1 = gelu(h @ W1 + b1)
    gemm_k<1, 0><<<dim3(32, 32), 256, 0, stream>>>(h, W1 + w1o, b1 + i * 2048, m1, nullptr, 2048, 2048, 512);
    // x = x + m1 @ W2 + b2
    gemm_k<0, 1><<<dim3(8, 32), 256, 0, stream>>>(m1, W2 + w1o, b2 + i * 512, x, x, 2048, 512, 2048);
    // x = LNf(x)  (in-place safe: row read to regs before write)
    ln_k<<<2048, 256, 0, stream>>>(x, x, lfg + i * 512, lfb + i * 512);
  }
}

// Round 2
// 5227.050 us; speedup vs baseline: 1.3068x; 1.3068x over previous
//
#include <hip/hip_runtime.h>
#include <math.h>

#define CC 512
#define NH 8
#define HD 64
#define NB 8
#define TT 256

// ---------------- LayerNorm: one block (256 thr) per row of 512 ----------------
__global__ __launch_bounds__(256) void ln_k(const float* __restrict__ in,
    float* __restrict__ out, const float* __restrict__ g, const float* __restrict__ b) {
  int row = blockIdx.x, t = threadIdx.x;
  const float* r = in + (size_t)row * CC;
  float v0 = r[t], v1 = r[t + 256];
  float s = v0 + v1;
  #pragma unroll
  for (int o = 32; o; o >>= 1) s += __shfl_xor(s, o);
  __shared__ float r1[4], r2[4];
  if ((t & 63) == 0) r1[t >> 6] = s;
  __syncthreads();
  float mu = (r1[0] + r1[1] + r1[2] + r1[3]) * (1.0f / CC);
  float d0 = v0 - mu, d1 = v1 - mu;
  float sq = d0 * d0 + d1 * d1;
  #pragma unroll
  for (int o = 32; o; o >>= 1) sq += __shfl_xor(sq, o);
  if ((t & 63) == 0) r2[t >> 6] = sq;
  __syncthreads();
  float var = (r2[0] + r2[1] + r2[2] + r2[3]) * (1.0f / CC);
  float inv = rsqrtf(var + 1e-5f);
  float* w = out + (size_t)row * CC;
  w[t]       = d0 * inv * g[t]       + b[t];
  w[t + 256] = d1 * inv * g[t + 256] + b[t + 256];
}

// ---------------- fp32 GEMM: out[M,N] = act(A[M,K] @ W[K,N] + bias) (+res) ----
template<int GELU, int RES>
__global__ __launch_bounds__(256) void gemm_k(const float* __restrict__ A,
    const float* __restrict__ W, const float* __restrict__ bias,
    float* __restrict__ out, const float* __restrict__ res,
    int M, int N, int K) {
  __shared__ float As[16][68];
  __shared__ float Bs[16][68];
  int bm = blockIdx.y << 6, bn = blockIdx.x << 6;
  int tid = threadIdx.x;
  int tm = (tid >> 4) << 2, tn = (tid & 15) << 2;
  int ar = tid >> 2, ac = (tid & 3) << 2;
  int br = tid >> 4, bc = (tid & 15) << 2;
  const float* Ap = A + (size_t)(bm + ar) * K + ac;
  const float* Wp = W + (size_t)br * N + bn + bc;
  float acc[4][4] = {};
  for (int k0 = 0; k0 < K; k0 += 16) {
    float4 a4 = *(const float4*)(Ap + k0);
    As[ac + 0][ar] = a4.x; As[ac + 1][ar] = a4.y;
    As[ac + 2][ar] = a4.z; As[ac + 3][ar] = a4.w;
    *(float4*)&Bs[br][bc] = *(const float4*)(Wp + (size_t)k0 * N);
    __syncthreads();
    #pragma unroll
    for (int kk = 0; kk < 16; kk++) {
      float4 av = *(const float4*)&As[kk][tm];
      float4 bv = *(const float4*)&Bs[kk][tn];
      acc[0][0] += av.x * bv.x; acc[0][1] += av.x * bv.y; acc[0][2] += av.x * bv.z; acc[0][3] += av.x * bv.w;
      acc[1][0] += av.y * bv.x; acc[1][1] += av.y * bv.y; acc[1][2] += av.y * bv.z; acc[1][3] += av.y * bv.w;
      acc[2][0] += av.z * bv.x; acc[2][1] += av.z * bv.y; acc[2][2] += av.z * bv.z; acc[2][3] += av.z * bv.w;
      acc[3][0] += av.w * bv.x; acc[3][1] += av.w * bv.y; acc[3][2] += av.w * bv.z; acc[3][3] += av.w * bv.w;
    }
    __syncthreads();
  }
  #pragma unroll
  for (int i = 0; i < 4; i++) {
    int rr = bm + tm + i;
    #pragma unroll
    for (int j = 0; j < 4; j++) {
      int ccol = bn + tn + j;
      float vv = acc[i][j] + bias[ccol];
      if (GELU) vv = 0.5f * vv * (1.0f + erff(vv * 0.70710678118654752f));
      if (RES)  vv += res[(size_t)rr * N + ccol];
      out[(size_t)rr * N + ccol] = vv;
    }
  }
}

// ---------------- Attention: 1 wave per (b,h,query-row); 4 waves/block --------
// TOPK: exact 64th-largest (counting dups) via MSB->LSB radix select on
// order-preserving uint32 keys, counts by ballot+popcount (no shfl chains).
// Kept (j,weight) pairs are ballot-compacted so PV touches only ~64 V rows.
template<int CAUSAL, int TOPK, int NT>
__global__ __launch_bounds__(256) void attn_k(const float* __restrict__ q,
    const float* __restrict__ k, const float* __restrict__ v, float* __restrict__ y) {
  const int Ts = NT * 64;
  int wid = threadIdx.x >> 6, lane = threadIdx.x & 63;
  int g = (blockIdx.x << 2) + wid;
  int b = g >> 11;            // / (NH*TT) = 2048
  int rem = g & 2047;
  int h = rem >> 8;           // / TT
  int qi = rem & 255;
  __shared__ float sw[4][NT * 64];           // weights (compacted if TOPK)
  __shared__ unsigned short kidx[4][TOPK ? NT * 64 : 1];
  __shared__ float qs[4][64];
  qs[wid][lane] = q[(size_t)(b * TT + qi) * CC + h * HD + lane];
  int jmax = CAUSAL ? (qi + 1) : Ts;
  const float* kb = k + (size_t)b * Ts * CC + h * HD;
  float sc[NT];
  float lmax = -3.0e38f;
  #pragma unroll
  for (int t = 0; t < NT; t++) {
    int j = lane + (t << 6);
    float acc;
    if (j < jmax) {
      const float* kr = kb + (size_t)j * CC;
      acc = 0.f;
      #pragma unroll
      for (int d = 0; d < 64; d += 4) {
        float4 k4 = *(const float4*)(kr + d);
        acc += qs[wid][d] * k4.x + qs[wid][d + 1] * k4.y
             + qs[wid][d + 2] * k4.z + qs[wid][d + 3] * k4.w;
      }
      acc *= 0.125f;  // 1/sqrt(64)
    } else {
      acc = -3.0e38f;
    }
    sc[t] = acc;
    lmax = fmaxf(lmax, acc);
  }
  float mx = lmax;
  #pragma unroll
  for (int o = 32; o; o >>= 1) mx = fmaxf(mx, __shfl_xor(mx, o));

  const float* vb = v + (size_t)b * Ts * CC + h * HD + lane;
  float oacc;

  if (TOPK) {
    // order-preserving key: larger float -> larger uint
    unsigned key[NT];
    #pragma unroll
    for (int t = 0; t < NT; t++) {
      unsigned u = __float_as_uint(sc[t]);
      key[t] = (u & 0x80000000u) ? ~u : (u | 0x80000000u);
    }
    // radix select: largest prefix with count(keys >= prefix) >= 64
    unsigned prefix = 0u;
    #pragma unroll
    for (int bit = 31; bit >= 0; bit--) {
      unsigned cand = prefix | (1u << bit);
      int cnt = 0;
      #pragma unroll
      for (int t = 0; t < NT; t++)
        cnt += __popcll(__ballot(key[t] >= cand));
      if (cnt >= 64) prefix = cand;
    }
    // compact kept (j, weight) pairs; wave-local, no block sync needed
    float psum = 0.f;
    int base = 0;
    #pragma unroll
    for (int t = 0; t < NT; t++) {
      bool keep = key[t] >= prefix;
      float wv = keep ? expf(sc[t] - mx) : 0.f;
      psum += wv;
      unsigned long long mask = __ballot(keep);
      if (keep) {
        int pos = base + (int)__popcll(mask & ((1ull << lane) - 1ull));
        kidx[wid][pos] = (unsigned short)(lane + (t << 6));
        sw[wid][pos] = wv;
      }
      base += (int)__popcll(mask);
    }
    #pragma unroll
    for (int o = 32; o; o >>= 1) psum += __shfl_xor(psum, o);
    float inv = 1.0f / psum;
    int nk = base;
    float a0 = 0.f, a1 = 0.f;
    int i = 0;
    for (; i + 1 < nk; i += 2) {
      int j0 = kidx[wid][i], j1 = kidx[wid][i + 1];
      float w0 = sw[wid][i], w1 = sw[wid][i + 1];
      a0 += w0 * vb[(size_t)j0 * CC];
      a1 += w1 * vb[(size_t)j1 * CC];
    }
    if (i < nk) a0 += sw[wid][i] * vb[(size_t)kidx[wid][i] * CC];
    oacc = (a0 + a1) * inv;
  } else {
    float psum = 0.f;
    #pragma unroll
    for (int t = 0; t < NT; t++) {
      int j = lane + (t << 6);
      float wv = (j < jmax) ? expf(sc[t] - mx) : 0.f;
      sw[wid][j] = wv;
      psum += wv;
    }
    #pragma unroll
    for (int o = 32; o; o >>= 1) psum += __shfl_xor(psum, o);
    float inv = 1.0f / psum;
    float a0 = 0.f, a1 = 0.f;
    int j = 0;
    for (; j + 1 < jmax; j += 2) {
      a0 += sw[wid][j]     * vb[(size_t)j * CC];
      a1 += sw[wid][j + 1] * vb[(size_t)(j + 1) * CC];
    }
    if (j < jmax) a0 += sw[wid][j] * vb[(size_t)j * CC];
    oacc = (a0 + a1) * inv;
  }
  y[(size_t)(b * TT + qi) * CC + h * HD + lane] = oacc;
}

extern "C" void kernel_launch(void* const* d_in, const int* in_sizes, int n_in,
                              void* d_out, int out_size, void* d_ws, size_t ws_size,
                              hipStream_t stream) {
  const float* id_x    = (const float*)d_in[0];
  const float* id_prev = (const float*)d_in[1];
  const float* frames  = (const float*)d_in[2];
  const float* Wq = (const float*)d_in[3];  const float* bq = (const float*)d_in[4];
  const float* Wk = (const float*)d_in[5];  const float* bk = (const float*)d_in[6];
  const float* Wv = (const float*)d_in[7];  const float* bv = (const float*)d_in[8];
  const float* Wo = (const float*)d_in[9];  const float* bo = (const float*)d_in[10];
  const float* W1 = (const float*)d_in[11]; const float* b1 = (const float*)d_in[12];
  const float* W2 = (const float*)d_in[13]; const float* b2 = (const float*)d_in[14];
  const float* l1g = (const float*)d_in[15]; const float* l1b = (const float*)d_in[16];
  const float* l2g = (const float*)d_in[17]; const float* l2b = (const float*)d_in[18];
  const float* lfg = (const float*)d_in[19]; const float* lfb = (const float*)d_in[20];

  float* x  = (float*)d_out;                 // running residual stream [2048,512]
  float* ws = (float*)d_ws;
  const size_t M1 = (size_t)2048 * 512;
  float* h  = ws;
  float* q  = ws + M1;
  float* yb = ws + 2 * M1;
  float* kb = ws + 3 * M1;                   // K [<=4096,512]
  float* vb = ws + 5 * M1;                   // V [<=4096,512]
  float* m1 = ws + 3 * M1;                   // MLP intermediate, aliases k/v

  hipMemcpyAsync(x, id_x, M1 * sizeof(float), hipMemcpyDeviceToDevice, stream);

  static const int ssrc[10] = {0, 0, 0, 0, 1, 1, 2, 2, 1, 1};

  for (int i = 0; i < 10; i++) {
    const float* kv; int Nkv;
    if (ssrc[i] == 0)      { kv = frames;  Nkv = 4096; }
    else if (ssrc[i] == 1) { kv = x;       Nkv = 2048; }
    else                   { kv = id_prev; Nkv = 2048; }

    const size_t wo = (size_t)i * 512 * 512;
    const size_t w1o = (size_t)i * 512 * 2048;

    ln_k<<<2048, 256, 0, stream>>>(x, h, l1g + i * 512, l1b + i * 512);
    gemm_k<0, 0><<<dim3(8, 32), 256, 0, stream>>>(h, Wq + wo, bq + i * 512, q, nullptr, 2048, 512, 512);
    gemm_k<0, 0><<<dim3(8, Nkv / 64), 256, 0, stream>>>(kv, Wk + wo, bk + i * 512, kb, nullptr, Nkv, 512, 512);
    gemm_k<0, 0><<<dim3(8, Nkv / 64), 256, 0, stream>>>(kv, Wv + wo, bv + i * 512, vb, nullptr, Nkv, 512, 512);
    if (ssrc[i] == 0)      attn_k<0, 1, 8><<<4096, 256, 0, stream>>>(q, kb, vb, yb);
    else if (ssrc[i] == 1) attn_k<1, 0, 4><<<4096, 256, 0, stream>>>(q, kb, vb, yb);
    else                   attn_k<0, 0, 4><<<4096, 256, 0, stream>>>(q, kb, vb, yb);
    gemm_k<0, 1><<<dim3(8, 32), 256, 0, stream>>>(yb, Wo + wo, bo + i * 512, x, x, 2048, 512, 512);
    ln_k<<<2048, 256, 0, stream>>>(x, h, l2g + i * 512, l2b + i * 512);
    gemm_k<1, 0><<<dim3(32, 32), 256, 0, stream>>>(h, W1 + w1o, b1 + i * 2048, m1, nullptr, 2048, 2048, 512);
    gemm_k<0, 1><<<dim3(8, 32), 256, 0, stream>>>(m1, W2 + w1o, b2 + i * 512, x, x, 2048, 512, 2048);
    ln_k<<<2048, 256, 0, stream>>>(x, x, lfg + i * 512, lfb + i * 512);
  }
}

// Round 3
// 2014.420 us; speedup vs baseline: 3.3909x; 2.5948x over previous
//
#include <hip/hip_runtime.h>
#include <math.h>

#define CC 512
#define NH 8
#define HD 64
#define TT 256

typedef __attribute__((ext_vector_type(8))) short short8v;
typedef __attribute__((ext_vector_type(4))) float f32x4;

__device__ inline unsigned short bfc(float f) {  // fp32 -> bf16 bits, RNE
  unsigned u = __float_as_uint(f);
  unsigned r = (u + 0x7fffu + ((u >> 16) & 1u)) >> 16;
  return (unsigned short)r;
}

// ---------------- LayerNorm ----------------
__global__ __launch_bounds__(256) void ln_k(const float* __restrict__ in,
    float* __restrict__ out, const float* __restrict__ g, const float* __restrict__ b) {
  int row = blockIdx.x, t = threadIdx.x;
  const float* r = in + (size_t)row * CC;
  float v0 = r[t], v1 = r[t + 256];
  float s = v0 + v1;
  #pragma unroll
  for (int o = 32; o; o >>= 1) s += __shfl_xor(s, o);
  __shared__ float r1[4], r2[4];
  if ((t & 63) == 0) r1[t >> 6] = s;
  __syncthreads();
  float mu = (r1[0] + r1[1] + r1[2] + r1[3]) * (1.0f / CC);
  float d0 = v0 - mu, d1 = v1 - mu;
  float sq = d0 * d0 + d1 * d1;
  #pragma unroll
  for (int o = 32; o; o >>= 1) sq += __shfl_xor(sq, o);
  if ((t & 63) == 0) r2[t >> 6] = sq;
  __syncthreads();
  float var = (r2[0] + r2[1] + r2[2] + r2[3]) * (1.0f / CC);
  float inv = rsqrtf(var + 1e-5f);
  float* w = out + (size_t)row * CC;
  w[t]       = d0 * inv * g[t]       + b[t];
  w[t + 256] = d1 * inv * g[t + 256] + b[t + 256];
}

// ---------------- per-layer weight transpose+convert: W[K][N] fp32 -> WT[N][K] bf16
__global__ __launch_bounds__(256) void transpose_w(
    const float* __restrict__ Wq, const float* __restrict__ Wk,
    const float* __restrict__ Wv, const float* __restrict__ Wo,
    const float* __restrict__ W1, const float* __restrict__ W2,
    int layer, unsigned short* __restrict__ wT) {
  int bid = blockIdx.x;
  const float* src; unsigned short* dst; int R, Cn, tile, lg;
  if (bid < 1024) {
    int seg = bid >> 8; tile = bid & 255; R = 512; Cn = 512; lg = 4;
    const float* s4[4] = {Wq, Wk, Wv, Wo};
    src = s4[seg] + (size_t)layer * 262144;
    dst = wT + (size_t)seg * 262144;
  } else if (bid < 2048) {
    tile = bid - 1024; R = 512; Cn = 2048; lg = 6;
    src = W1 + (size_t)layer * 1048576; dst = wT + 1048576;
  } else {
    tile = bid - 2048; R = 2048; Cn = 512; lg = 4;
    src = W2 + (size_t)layer * 1048576; dst = wT + 2097152;
  }
  int trb = tile >> lg, tcb = tile & ((1 << lg) - 1);
  __shared__ float tl[32][33];
  int t = threadIdx.x;
  int r = t >> 3, c4 = (t & 7) << 2;
  const float* sp = src + (size_t)(trb * 32 + r) * Cn + tcb * 32 + c4;
  float4 fv = *(const float4*)sp;
  tl[r][c4] = fv.x; tl[r][c4 + 1] = fv.y; tl[r][c4 + 2] = fv.z; tl[r][c4 + 3] = fv.w;
  __syncthreads();
  unsigned short* dp = dst + (size_t)(tcb * 32 + r) * R + trb * 32 + c4;
  ushort4 ov;
  ov.x = bfc(tl[c4][r]); ov.y = bfc(tl[c4 + 1][r]);
  ov.z = bfc(tl[c4 + 2][r]); ov.w = bfc(tl[c4 + 3][r]);
  *(ushort4*)dp = ov;
}

// ---------------- bf16 MFMA GEMM: out[M,N] = act(A@W + bias) (+res) ----------
// A [M][K] fp32 (converted to bf16 during LDS staging), WT [N][K] bf16.
// 64x64 block tile, 4 waves in 2x2, each wave 32x32 via 2x2 mfma_f32_16x16x32_bf16.
template<int GELU, int RES>
__global__ __launch_bounds__(256) void gemm_mfma(
    const float* __restrict__ A, const unsigned short* __restrict__ WT,
    const float* __restrict__ bias, float* __restrict__ out,
    const float* __restrict__ res, int M, int N, int K) {
  __shared__ unsigned short As[64][40];  // [row][k], stride 80B (16B-mult)
  __shared__ unsigned short Bs[64][40];  // [col][k]
  int tid = threadIdx.x, lane = tid & 63, wid = tid >> 6;
  int bm = blockIdx.y << 6, bn = blockIdx.x << 6;
  int wr = (wid >> 1) << 5, wc = (wid & 1) << 5;
  int sr = tid >> 2, sk = (tid & 3) << 3;      // staging: row, k-offset (8 elems)
  const float* Ap = A + (size_t)(bm + sr) * K + sk;
  const unsigned short* Bp = WT + (size_t)(bn + sr) * K + sk;
  int fr = lane & 15, kh = (lane >> 4) << 3;   // frag row/col + k-half
  f32x4 acc[2][2] = {};
  for (int k0 = 0; k0 < K; k0 += 32) {
    float4 a0 = *(const float4*)(Ap + k0);
    float4 a1 = *(const float4*)(Ap + k0 + 4);
    float4 braw = *(const float4*)(Bp + k0);   // 8 bf16
    ushort4 w0; w0.x = bfc(a0.x); w0.y = bfc(a0.y); w0.z = bfc(a0.z); w0.w = bfc(a0.w);
    ushort4 w1; w1.x = bfc(a1.x); w1.y = bfc(a1.y); w1.z = bfc(a1.z); w1.w = bfc(a1.w);
    *(ushort4*)&As[sr][sk]     = w0;
    *(ushort4*)&As[sr][sk + 4] = w1;
    *(float4*)&Bs[sr][sk]      = braw;
    __syncthreads();
    short8v af0 = *(const short8v*)&As[wr + fr][kh];
    short8v af1 = *(const short8v*)&As[wr + 16 + fr][kh];
    short8v bf0 = *(const short8v*)&Bs[wc + fr][kh];
    short8v bf1 = *(const short8v*)&Bs[wc + 16 + fr][kh];
    acc[0][0] = __builtin_amdgcn_mfma_f32_16x16x32_bf16(af0, bf0, acc[0][0], 0, 0, 0);
    acc[0][1] = __builtin_amdgcn_mfma_f32_16x16x32_bf16(af0, bf1, acc[0][1], 0, 0, 0);
    acc[1][0] = __builtin_amdgcn_mfma_f32_16x16x32_bf16(af1, bf0, acc[1][0], 0, 0, 0);
    acc[1][1] = __builtin_amdgcn_mfma_f32_16x16x32_bf16(af1, bf1, acc[1][1], 0, 0, 0);
    __syncthreads();
  }
  int fq = lane >> 4;
  #pragma unroll
  for (int m = 0; m < 2; m++) {
    #pragma unroll
    for (int n = 0; n < 2; n++) {
      int row0 = bm + wr + m * 16 + fq * 4;
      int col  = bn + wc + n * 16 + fr;
      #pragma unroll
      for (int r = 0; r < 4; r++) {
        float vv = acc[m][n][r] + bias[col];
        if (GELU) vv = 0.5f * vv * (1.0f + erff(vv * 0.70710678118654752f));
        if (RES)  vv += res[(size_t)(row0 + r) * N + col];
        out[(size_t)(row0 + r) * N + col] = vv;
      }
    }
  }
}

// ---------------- fp32 GEMM fallback (small ws) ----------------
template<int GELU, int RES>
__global__ __launch_bounds__(256) void gemm_k(const float* __restrict__ A,
    const float* __restrict__ W, const float* __restrict__ bias,
    float* __restrict__ out, const float* __restrict__ res,
    int M, int N, int K) {
  __shared__ float Asm[16][68];
  __shared__ float Bsm[16][68];
  int bm = blockIdx.y << 6, bn = blockIdx.x << 6;
  int tid = threadIdx.x;
  int tm = (tid >> 4) << 2, tn = (tid & 15) << 2;
  int ar = tid >> 2, ac = (tid & 3) << 2;
  int br = tid >> 4, bc = (tid & 15) << 2;
  const float* Ap = A + (size_t)(bm + ar) * K + ac;
  const float* Wp = W + (size_t)br * N + bn + bc;
  float acc[4][4] = {};
  for (int k0 = 0; k0 < K; k0 += 16) {
    float4 a4 = *(const float4*)(Ap + k0);
    Asm[ac + 0][ar] = a4.x; Asm[ac + 1][ar] = a4.y;
    Asm[ac + 2][ar] = a4.z; Asm[ac + 3][ar] = a4.w;
    *(float4*)&Bsm[br][bc] = *(const float4*)(Wp + (size_t)k0 * N);
    __syncthreads();
    #pragma unroll
    for (int kk = 0; kk < 16; kk++) {
      float4 av = *(const float4*)&Asm[kk][tm];
      float4 bv = *(const float4*)&Bsm[kk][tn];
      acc[0][0] += av.x * bv.x; acc[0][1] += av.x * bv.y; acc[0][2] += av.x * bv.z; acc[0][3] += av.x * bv.w;
      acc[1][0] += av.y * bv.x; acc[1][1] += av.y * bv.y; acc[1][2] += av.y * bv.z; acc[1][3] += av.y * bv.w;
      acc[2][0] += av.z * bv.x; acc[2][1] += av.z * bv.y; acc[2][2] += av.z * bv.z; acc[2][3] += av.z * bv.w;
      acc[3][0] += av.w * bv.x; acc[3][1] += av.w * bv.y; acc[3][2] += av.w * bv.z; acc[3][3] += av.w * bv.w;
    }
    __syncthreads();
  }
  #pragma unroll
  for (int i = 0; i < 4; i++) {
    int rr = bm + tm + i;
    #pragma unroll
    for (int j = 0; j < 4; j++) {
      int ccol = bn + tn + j;
      float vv = acc[i][j] + bias[ccol];
      if (GELU) vv = 0.5f * vv * (1.0f + erff(vv * 0.70710678118654752f));
      if (RES)  vv += res[(size_t)rr * N + ccol];
      out[(size_t)rr * N + ccol] = vv;
    }
  }
}

// ---------------- Attention: block = 4 waves sharing (b,h), K staged in LDS ---
template<int CAUSAL, int TOPK, int NT>
__global__ __launch_bounds__(256) void attn_k(const float* __restrict__ q,
    const float* __restrict__ k, const float* __restrict__ v, float* __restrict__ y) {
  const int Ts = NT * 64;
  int tid = threadIdx.x;
  int wid = tid >> 6, lane = tid & 63;
  int g = (blockIdx.x << 2) + wid;
  int b = g >> 11;
  int h = (g >> 8) & 7;
  int qi = g & 255;
  __shared__ float Ks[64][66];               // stride 66 floats: float2 reads 2-way-free
  __shared__ float sw[4][NT * 64];
  __shared__ unsigned short kidx[4][TOPK ? NT * 64 : 4];
  __shared__ float qs[4][64];
  qs[wid][lane] = q[(size_t)(b * TT + qi) * CC + h * HD + lane];
  int jmax = CAUSAL ? (qi + 1) : Ts;
  const float* kb = k + (size_t)b * Ts * CC + h * HD;
  int srow = tid >> 2, scol = (tid & 3) << 4;  // staging: 64 rows x 64 cols
  float sc[NT];
  float lmax = -3.0e38f;
  for (int t = 0; t < NT; t++) {
    __syncthreads();
    const float* sp = kb + (size_t)((t << 6) + srow) * CC + scol;
    float4 f0 = *(const float4*)(sp);
    float4 f1 = *(const float4*)(sp + 4);
    float4 f2 = *(const float4*)(sp + 8);
    float4 f3 = *(const float4*)(sp + 12);
    *(float2*)&Ks[srow][scol]      = make_float2(f0.x, f0.y);
    *(float2*)&Ks[srow][scol + 2]  = make_float2(f0.z, f0.w);
    *(float2*)&Ks[srow][scol + 4]  = make_float2(f1.x, f1.y);
    *(float2*)&Ks[srow][scol + 6]  = make_float2(f1.z, f1.w);
    *(float2*)&Ks[srow][scol + 8]  = make_float2(f2.x, f2.y);
    *(float2*)&Ks[srow][scol + 10] = make_float2(f2.z, f2.w);
    *(float2*)&Ks[srow][scol + 12] = make_float2(f3.x, f3.y);
    *(float2*)&Ks[srow][scol + 14] = make_float2(f3.z, f3.w);
    __syncthreads();
    float accv = -3.0e38f;
    int j = (t << 6) + lane;
    if (j < jmax) {
      float a = 0.f;
      #pragma unroll
      for (int d = 0; d < 64; d += 2) {
        float2 kv2 = *(const float2*)&Ks[lane][d];
        a += qs[wid][d] * kv2.x + qs[wid][d + 1] * kv2.y;
      }
      accv = a * 0.125f;
    }
    sc[t] = accv;
    lmax = fmaxf(lmax, accv);
  }
  float mx = lmax;
  #pragma unroll
  for (int o = 32; o; o >>= 1) mx = fmaxf(mx, __shfl_xor(mx, o));

  const float* vb = v + (size_t)b * Ts * CC + h * HD + lane;
  float oacc;

  if (TOPK) {
    unsigned key[NT];
    #pragma unroll
    for (int t = 0; t < NT; t++) {
      unsigned u = __float_as_uint(sc[t]);
      key[t] = (u & 0x80000000u) ? ~u : (u | 0x80000000u);
    }
    unsigned prefix = 0u;
    #pragma unroll
    for (int bit = 31; bit >= 0; bit--) {
      unsigned cand = prefix | (1u << bit);
      int cnt = 0;
      #pragma unroll
      for (int t = 0; t < NT; t++)
        cnt += __popcll(__ballot(key[t] >= cand));
      if (cnt >= 64) prefix = cand;
    }
    float psum = 0.f;
    int base = 0;
    #pragma unroll
    for (int t = 0; t < NT; t++) {
      bool keep = key[t] >= prefix;
      float wv = keep ? expf(sc[t] - mx) : 0.f;
      psum += wv;
      unsigned long long mask = __ballot(keep);
      if (keep) {
        int pos = base + (int)__popcll(mask & ((1ull << lane) - 1ull));
        kidx[wid][pos] = (unsigned short)(lane + (t << 6));
        sw[wid][pos] = wv;
      }
      base += (int)__popcll(mask);
    }
    #pragma unroll
    for (int o = 32; o; o >>= 1) psum += __shfl_xor(psum, o);
    float inv = 1.0f / psum;
    int nk = base;
    float a0 = 0.f, a1 = 0.f;
    int i = 0;
    for (; i + 1 < nk; i += 2) {
      int j0 = kidx[wid][i], j1 = kidx[wid][i + 1];
      float w0 = sw[wid][i], w1 = sw[wid][i + 1];
      a0 += w0 * vb[(size_t)j0 * CC];
      a1 += w1 * vb[(size_t)j1 * CC];
    }
    if (i < nk) a0 += sw[wid][i] * vb[(size_t)kidx[wid][i] * CC];
    oacc = (a0 + a1) * inv;
  } else {
    float psum = 0.f;
    #pragma unroll
    for (int t = 0; t < NT; t++) {
      int j = lane + (t << 6);
      float wv = (j < jmax) ? expf(sc[t] - mx) : 0.f;
      sw[wid][j] = wv;
      psum += wv;
    }
    #pragma unroll
    for (int o = 32; o; o >>= 1) psum += __shfl_xor(psum, o);
    float inv = 1.0f / psum;
    float a0 = 0.f, a1 = 0.f;
    int j = 0;
    for (; j + 1 < jmax; j += 2) {
      a0 += sw[wid][j]     * vb[(size_t)j * CC];
      a1 += sw[wid][j + 1] * vb[(size_t)(j + 1) * CC];
    }
    if (j < jmax) a0 += sw[wid][j] * vb[(size_t)j * CC];
    oacc = (a0 + a1) * inv;
  }
  y[(size_t)(b * TT + qi) * CC + h * HD + lane] = oacc;
}

extern "C" void kernel_launch(void* const* d_in, const int* in_sizes, int n_in,
                              void* d_out, int out_size, void* d_ws, size_t ws_size,
                              hipStream_t stream) {
  const float* id_x    = (const float*)d_in[0];
  const float* id_prev = (const float*)d_in[1];
  const float* frames  = (const float*)d_in[2];
  const float* Wq = (const float*)d_in[3];  const float* bq = (const float*)d_in[4];
  const float* Wk = (const float*)d_in[5];  const float* bk = (const float*)d_in[6];
  const float* Wv = (const float*)d_in[7];  const float* bv = (const float*)d_in[8];
  const float* Wo = (const float*)d_in[9];  const float* bo = (const float*)d_in[10];
  const float* W1 = (const float*)d_in[11]; const float* b1 = (const float*)d_in[12];
  const float* W2 = (const float*)d_in[13]; const float* b2 = (const float*)d_in[14];
  const float* l1g = (const float*)d_in[15]; const float* l1b = (const float*)d_in[16];
  const float* l2g = (const float*)d_in[17]; const float* l2b = (const float*)d_in[18];
  const float* lfg = (const float*)d_in[19]; const float* lfb = (const float*)d_in[20];

  float* x  = (float*)d_out;                 // running residual stream [2048,512]
  float* ws = (float*)d_ws;
  const size_t M1 = (size_t)2048 * 512;
  float* h  = ws;
  float* q  = ws + M1;
  float* yb = ws + 2 * M1;
  float* kb = ws + 3 * M1;                   // K [<=4096,512]
  float* vb = ws + 5 * M1;                   // V [<=4096,512]
  float* m1 = ws + 3 * M1;                   // MLP intermediate, aliases k/v
  unsigned short* wT = (unsigned short*)(ws + 7 * M1);  // 3,145,728 bf16

  const size_t need = 7 * M1 * 4 + (size_t)3145728 * 2;
  const bool mfma = (ws_size >= need);

  hipMemcpyAsync(x, id_x, M1 * sizeof(float), hipMemcpyDeviceToDevice, stream);

  static const int ssrc[10] = {0, 0, 0, 0, 1, 1, 2, 2, 1, 1};

  for (int i = 0; i < 10; i++) {
    const float* kv; int Nkv;
    if (ssrc[i] == 0)      { kv = frames;  Nkv = 4096; }
    else if (ssrc[i] == 1) { kv = x;       Nkv = 2048; }
    else                   { kv = id_prev; Nkv = 2048; }

    const size_t wo = (size_t)i * 512 * 512;
    const size_t w1o = (size_t)i * 512 * 2048;

    ln_k<<<2048, 256, 0, stream>>>(x, h, l1g + i * 512, l1b + i * 512);

    if (mfma) {
      transpose_w<<<3072, 256, 0, stream>>>(Wq, Wk, Wv, Wo, W1, W2, i, wT);
      unsigned short* wqT = wT;
      unsigned short* wkT = wT + 262144;
      unsigned short* wvT = wT + 524288;
      unsigned short* woT = wT + 786432;
      unsigned short* w1T = wT + 1048576;
      unsigned short* w2T = wT + 2097152;
      gemm_mfma<0, 0><<<dim3(8, 32), 256, 0, stream>>>(h, wqT, bq + i * 512, q, nullptr, 2048, 512, 512);
      gemm_mfma<0, 0><<<dim3(8, Nkv / 64), 256, 0, stream>>>(kv, wkT, bk + i * 512, kb, nullptr, Nkv, 512, 512);
      gemm_mfma<0, 0><<<dim3(8, Nkv / 64), 256, 0, stream>>>(kv, wvT, bv + i * 512, vb, nullptr, Nkv, 512, 512);
      if (ssrc[i] == 0)      attn_k<0, 1, 8><<<4096, 256, 0, stream>>>(q, kb, vb, yb);
      else if (ssrc[i] == 1) attn_k<1, 0, 4><<<4096, 256, 0, stream>>>(q, kb, vb, yb);
      else                   attn_k<0, 0, 4><<<4096, 256, 0, stream>>>(q, kb, vb, yb);
      gemm_mfma<0, 1><<<dim3(8, 32), 256, 0, stream>>>(yb, woT, bo + i * 512, x, x, 2048, 512, 512);
      ln_k<<<2048, 256, 0, stream>>>(x, h, l2g + i * 512, l2b + i * 512);
      gemm_mfma<1, 0><<<dim3(32, 32), 256, 0, stream>>>(h, w1T, b1 + i * 2048, m1, nullptr, 2048, 2048, 512);
      gemm_mfma<0, 1><<<dim3(8, 32), 256, 0, stream>>>(m1, w2T, b2 + i * 512, x, x, 2048, 512, 2048);
    } else {
      gemm_k<0, 0><<<dim3(8, 32), 256, 0, stream>>>(h, Wq + wo, bq + i * 512, q, nullptr, 2048, 512, 512);
      gemm_k<0, 0><<<dim3(8, Nkv / 64), 256, 0, stream>>>(kv, Wk + wo, bk + i * 512, kb, nullptr, Nkv, 512, 512);
      gemm_k<0, 0><<<dim3(8, Nkv / 64), 256, 0, stream>>>(kv, Wv + wo, bv + i * 512, vb, nullptr, Nkv, 512, 512);
      if (ssrc[i] == 0)      attn_k<0, 1, 8><<<4096, 256, 0, stream>>>(q, kb, vb, yb);
      else if (ssrc[i] == 1) attn_k<1, 0, 4><<<4096, 256, 0, stream>>>(q, kb, vb, yb);
      else                   attn_k<0, 0, 4><<<4096, 256, 0, stream>>>(q, kb, vb, yb);
      gemm_k<0, 1><<<dim3(8, 32), 256, 0, stream>>>(yb, Wo + wo, bo + i * 512, x, x, 2048, 512, 512);
      ln_k<<<2048, 256, 0, stream>>>(x, h, l2g + i * 512, l2b + i * 512);
      gemm_k<1, 0><<<dim3(32, 32), 256, 0, stream>>>(h, W1 + w1o, b1 + i * 2048, m1, nullptr, 2048, 2048, 512);
      gemm_k<0, 1><<<dim3(8, 32), 256, 0, stream>>>(m1, W2 + w1o, b2 + i * 512, x, x, 2048, 512, 2048);
    }
    ln_k<<<2048, 256, 0, stream>>>(x, x, lfg + i * 512, lfb + i * 512);
  }
}

// Round 5
// 1691.429 us; speedup vs baseline: 4.0384x; 1.1910x over previous
//
#include <hip/hip_runtime.h>
#include <math.h>

#define CC 512
#define NH 8
#define HD 64
#define TT 256

typedef __attribute__((ext_vector_type(8))) short short8v;
typedef __attribute__((ext_vector_type(4))) float f32x4;

__device__ inline unsigned short bfc(float f) {  // fp32 -> bf16, RNE
  unsigned u = __float_as_uint(f);
  return (unsigned short)((u + 0x7fffu + ((u >> 16) & 1u)) >> 16);
}
__device__ inline float b2f(unsigned short s) {
  return __uint_as_float((unsigned)s << 16);
}

// ---------------- prep: x=id_x; fb=bf16(frames); pb=bf16(id_prev) ------------
__global__ __launch_bounds__(256) void prep_k(const float* __restrict__ id_x,
    const float* __restrict__ frames, const float* __restrict__ id_prev,
    float* __restrict__ x, unsigned short* __restrict__ fb,
    unsigned short* __restrict__ pb) {
  int i = blockIdx.x * 256 + threadIdx.x;  // 0..1048575
  if (i < 262144) {
    ((float4*)x)[i] = ((const float4*)id_x)[i];
  } else if (i < 786432) {
    int j = i - 262144;
    float4 f = ((const float4*)frames)[j];
    ushort4 o; o.x = bfc(f.x); o.y = bfc(f.y); o.z = bfc(f.z); o.w = bfc(f.w);
    ((ushort4*)fb)[j] = o;
  } else {
    int j = i - 786432;
    float4 f = ((const float4*)id_prev)[j];
    ushort4 o; o.x = bfc(f.x); o.y = bfc(f.y); o.z = bfc(f.z); o.w = bfc(f.w);
    ((ushort4*)pb)[j] = o;
  }
}

// ---------------- LayerNorm variants ----------------
__global__ __launch_bounds__(256) void ln_bf(const float* __restrict__ in,
    unsigned short* __restrict__ out, const float* __restrict__ g, const float* __restrict__ b) {
  int row = blockIdx.x, t = threadIdx.x;
  const float* r = in + (size_t)row * CC;
  float v0 = r[t], v1 = r[t + 256];
  float s = v0 + v1;
  #pragma unroll
  for (int o = 32; o; o >>= 1) s += __shfl_xor(s, o);
  __shared__ float r1[4], r2[4];
  if ((t & 63) == 0) r1[t >> 6] = s;
  __syncthreads();
  float mu = (r1[0] + r1[1] + r1[2] + r1[3]) * (1.0f / CC);
  float d0 = v0 - mu, d1 = v1 - mu;
  float sq = d0 * d0 + d1 * d1;
  #pragma unroll
  for (int o = 32; o; o >>= 1) sq += __shfl_xor(sq, o);
  if ((t & 63) == 0) r2[t >> 6] = sq;
  __syncthreads();
  float inv = rsqrtf((r2[0] + r2[1] + r2[2] + r2[3]) * (1.0f / CC) + 1e-5f);
  out[(size_t)row * CC + t]       = bfc(d0 * inv * g[t] + b[t]);
  out[(size_t)row * CC + t + 256] = bfc(d1 * inv * g[t + 256] + b[t + 256]);
}

__global__ __launch_bounds__(256) void ln_final(const float* __restrict__ in,
    float* __restrict__ out, const float* __restrict__ g, const float* __restrict__ b) {
  int row = blockIdx.x, t = threadIdx.x;
  const float* r = in + (size_t)row * CC;
  float v0 = r[t], v1 = r[t + 256];
  float s = v0 + v1;
  #pragma unroll
  for (int o = 32; o; o >>= 1) s += __shfl_xor(s, o);
  __shared__ float r1[4], r2[4];
  if ((t & 63) == 0) r1[t >> 6] = s;
  __syncthreads();
  float mu = (r1[0] + r1[1] + r1[2] + r1[3]) * (1.0f / CC);
  float d0 = v0 - mu, d1 = v1 - mu;
  float sq = d0 * d0 + d1 * d1;
  #pragma unroll
  for (int o = 32; o; o >>= 1) sq += __shfl_xor(sq, o);
  if ((t & 63) == 0) r2[t >> 6] = sq;
  __syncthreads();
  float inv = rsqrtf((r2[0] + r2[1] + r2[2] + r2[3]) * (1.0f / CC) + 1e-5f);
  out[(size_t)row * CC + t]       = d0 * inv * g[t] + b[t];
  out[(size_t)row * CC + t + 256] = d1 * inv * g[t + 256] + b[t + 256];
}

// LNf then LN1-of-next-layer: writes x fp32, xb bf16, h bf16
__global__ __launch_bounds__(256) void ln_chain(const float* __restrict__ in,
    float* __restrict__ xout, unsigned short* __restrict__ xb,
    const float* __restrict__ gf, const float* __restrict__ bf,
    const float* __restrict__ g1, const float* __restrict__ b1,
    unsigned short* __restrict__ hout) {
  int row = blockIdx.x, t = threadIdx.x;
  const float* r = in + (size_t)row * CC;
  float v0 = r[t], v1 = r[t + 256];
  float s = v0 + v1;
  #pragma unroll
  for (int o = 32; o; o >>= 1) s += __shfl_xor(s, o);
  __shared__ float r1[4], r2[4];
  if ((t & 63) == 0) r1[t >> 6] = s;
  __syncthreads();
  float mu = (r1[0] + r1[1] + r1[2] + r1[3]) * (1.0f / CC);
  float d0 = v0 - mu, d1 = v1 - mu;
  float sq = d0 * d0 + d1 * d1;
  #pragma unroll
  for (int o = 32; o; o >>= 1) sq += __shfl_xor(sq, o);
  if ((t & 63) == 0) r2[t >> 6] = sq;
  __syncthreads();
  float inv = rsqrtf((r2[0] + r2[1] + r2[2] + r2[3]) * (1.0f / CC) + 1e-5f);
  float xf0 = d0 * inv * gf[t] + bf[t];
  float xf1 = d1 * inv * gf[t + 256] + bf[t + 256];
  xout[(size_t)row * CC + t]       = xf0;
  xout[(size_t)row * CC + t + 256] = xf1;
  xb[(size_t)row * CC + t]         = bfc(xf0);
  xb[(size_t)row * CC + t + 256]   = bfc(xf1);
  __syncthreads();
  // second LN on (xf0, xf1)
  float s2 = xf0 + xf1;
  #pragma unroll
  for (int o = 32; o; o >>= 1) s2 += __shfl_xor(s2, o);
  if ((t & 63) == 0) r1[t >> 6] = s2;
  __syncthreads();
  float mu2 = (r1[0] + r1[1] + r1[2] + r1[3]) * (1.0f / CC);
  float e0 = xf0 - mu2, e1 = xf1 - mu2;
  float sq2 = e0 * e0 + e1 * e1;
  #pragma unroll
  for (int o = 32; o; o >>= 1) sq2 += __shfl_xor(sq2, o);
  if ((t & 63) == 0) r2[t >> 6] = sq2;
  __syncthreads();
  float inv2 = rsqrtf((r2[0] + r2[1] + r2[2] + r2[3]) * (1.0f / CC) + 1e-5f);
  hout[(size_t)row * CC + t]       = bfc(e0 * inv2 * g1[t] + b1[t]);
  hout[(size_t)row * CC + t + 256] = bfc(e1 * inv2 * g1[t + 256] + b1[t + 256]);
}

// ---------------- weight transpose+convert: W[K][N] fp32 -> WT[N][K] bf16 -----
__global__ __launch_bounds__(256) void transpose_w(
    const float* __restrict__ Wq, const float* __restrict__ Wk,
    const float* __restrict__ Wv, const float* __restrict__ Wo,
    const float* __restrict__ W1, const float* __restrict__ W2,
    int layer_base, unsigned short* __restrict__ wT) {
  int lz = blockIdx.x / 3072;
  int layer = layer_base + lz;
  int bid = blockIdx.x - lz * 3072;
  unsigned short* wTl = wT + (size_t)lz * 3145728;
  const float* src; unsigned short* dst; int R, Cn, tile, lg;
  if (bid < 1024) {
    int seg = bid >> 8; tile = bid & 255; R = 512; Cn = 512; lg = 4;
    const float* s4[4] = {Wq, Wk, Wv, Wo};
    src = s4[seg] + (size_t)layer * 262144;
    dst = wTl + (size_t)seg * 262144;
  } else if (bid < 2048) {
    tile = bid - 1024; R = 512; Cn = 2048; lg = 6;
    src = W1 + (size_t)layer * 1048576; dst = wTl + 1048576;
  } else {
    tile = bid - 2048; R = 2048; Cn = 512; lg = 4;
    src = W2 + (size_t)layer * 1048576; dst = wTl + 2097152;
  }
  int trb = tile >> lg, tcb = tile & ((1 << lg) - 1);
  __shared__ float tl[32][33];
  int t = threadIdx.x;
  int r = t >> 3, c4 = (t & 7) << 2;
  const float* sp = src + (size_t)(trb * 32 + r) * Cn + tcb * 32 + c4;
  float4 fv = *(const float4*)sp;
  tl[r][c4] = fv.x; tl[r][c4 + 1] = fv.y; tl[r][c4 + 2] = fv.z; tl[r][c4 + 3] = fv.w;
  __syncthreads();
  unsigned short* dp = dst + (size_t)(tcb * 32 + r) * R + trb * 32 + c4;
  ushort4 ov;
  ov.x = bfc(tl[c4][r]); ov.y = bfc(tl[c4 + 1][r]);
  ov.z = bfc(tl[c4 + 2][r]); ov.w = bfc(tl[c4 + 3][r]);
  *(ushort4*)dp = ov;
}

// ---------------- bf16 MFMA GEMM --------------------------------------------
// A bf16 [M][K], WT bf16 [N][K]; out = act(A@W + bias)(+res); BN=64, BK=64.
// 4 waves 2x2; wave tile (BM/2)x32; XOR-swizzled LDS, conflict-free b128.
template<int BM, int GELU, int RES, int OUTBF>
__global__ __launch_bounds__(256) void gemm_bf(
    const unsigned short* __restrict__ A, const unsigned short* __restrict__ WT,
    const float* __restrict__ bias, void* __restrict__ outp,
    const float* __restrict__ res, int M, int N, int K) {
  __shared__ unsigned short As[BM * 64];
  __shared__ unsigned short Bs[64 * 64];
  const int tid = threadIdx.x, lane = tid & 63, wid = tid >> 6;
  const int bm = blockIdx.y * BM, bn = blockIdx.x << 6;
  const int wm = (wid >> 1) * (BM / 2), wn = (wid & 1) << 5;
  constexpr int MF = BM / 32;
  f32x4 acc[MF][2] = {};
  const int fr = lane & 15, fq = lane >> 4;
  for (int k0 = 0; k0 < K; k0 += 64) {
    if (k0) __syncthreads();
    #pragma unroll
    for (int i = 0; i < BM / 32; i++) {
      int gl = tid + (i << 8);
      int row = gl >> 3, gc = gl & 7;
      short8v d = *(const short8v*)(A + (size_t)(bm + row) * K + k0 + (gc << 3));
      *(short8v*)((char*)As + ((((row << 7) + (gc << 4))) ^ ((row & 7) << 4))) = d;
    }
    #pragma unroll
    for (int i = 0; i < 2; i++) {
      int gl = tid + (i << 8);
      int row = gl >> 3, gc = gl & 7;
      short8v d = *(const short8v*)(WT + (size_t)(bn + row) * K + k0 + (gc << 3));
      *(short8v*)((char*)Bs + ((((row << 7) + (gc << 4))) ^ ((row & 7) << 4))) = d;
    }
    __syncthreads();
    short8v af[MF][2], bf2[2][2];
    #pragma unroll
    for (int mf = 0; mf < MF; mf++)
      #pragma unroll
      for (int ks = 0; ks < 2; ks++) {
        int r = wm + mf * 16 + fr;
        int c = (ks << 2) + fq;
        af[mf][ks] = *(const short8v*)((const char*)As + ((((r << 7) + (c << 4))) ^ ((r & 7) << 4)));
      }
    #pragma unroll
    for (int nf = 0; nf < 2; nf++)
      #pragma unroll
      for (int ks = 0; ks < 2; ks++) {
        int r = wn + nf * 16 + fr;
        int c = (ks << 2) + fq;
        bf2[nf][ks] = *(const short8v*)((const char*)Bs + ((((r << 7) + (c << 4))) ^ ((r & 7) << 4)));
      }
    #pragma unroll
    for (int mf = 0; mf < MF; mf++)
      #pragma unroll
      for (int nf = 0; nf < 2; nf++) {
        acc[mf][nf] = __builtin_amdgcn_mfma_f32_16x16x32_bf16(af[mf][0], bf2[nf][0], acc[mf][nf], 0, 0, 0);
        acc[mf][nf] = __builtin_amdgcn_mfma_f32_16x16x32_bf16(af[mf][1], bf2[nf][1], acc[mf][nf], 0, 0, 0);
      }
  }
  #pragma unroll
  for (int mf = 0; mf < MF; mf++)
    #pragma unroll
    for (int nf = 0; nf < 2; nf++) {
      int col = bn + wn + nf * 16 + fr;
      float bia = bias[col];
      #pragma unroll
      for (int rr = 0; rr < 4; rr++) {
        int row = bm + wm + mf * 16 + fq * 4 + rr;
        float vv = acc[mf][nf][rr] + bia;
        if (GELU) vv = 0.5f * vv * (1.0f + erff(vv * 0.70710678118654752f));
        if (RES)  vv += res[(size_t)row * N + col];
        if (OUTBF) ((unsigned short*)outp)[(size_t)row * N + col] = bfc(vv);
        else       ((float*)outp)[(size_t)row * N + col] = vv;
      }
    }
}

// ---------------- Attention: 512 thr = 8 waves x 1 q-row, shared (b,h) -------
// K tile bf16->fp32 staged in XOR-swizzled LDS (conflict-free b128 reads);
// q fp32 in registers; radix-select exact top-64 threshold; bf16 V gather.
template<int CAUSAL, int TOPK, int NT>
__global__ __launch_bounds__(512) void attn_k(
    const float* __restrict__ qf, const unsigned short* __restrict__ kbuf,
    const unsigned short* __restrict__ vbuf, unsigned short* __restrict__ yb) {
  const int Ts = NT * 64;
  int tid = threadIdx.x, lane = tid & 63, wid = tid >> 6;
  int bid = blockIdx.x;
  int w = ((bid & 7) << 8) | (bid >> 3);   // XCD swizzle (2048 blocks, bijective)
  int base = w << 3;
  int b = base >> 11, h = (base >> 8) & 7, q0 = base & 255;
  int qi = q0 + wid;
  __shared__ float Ks[64 * 64];            // 16KB, swizzled
  __shared__ float qs[8][64];
  __shared__ float swt[8][NT * 64];
  __shared__ unsigned short kidx[TOPK ? 8 : 1][TOPK ? NT * 64 : 1];
  if (tid < 128) {
    int row = tid >> 4, gc = tid & 15;
    ((float4*)qs[row])[gc] = *(const float4*)(qf + (size_t)(b * TT + q0 + row) * CC + h * HD + (gc << 2));
  }
  __syncthreads();
  float4 qv[16];
  #pragma unroll
  for (int c = 0; c < 16; c++) qv[c] = ((float4*)qs[wid])[c];
  int jmax = CAUSAL ? (qi + 1) : Ts;
  int nte = CAUSAL ? ((q0 + 8 + 63) >> 6) : NT;
  const unsigned short* kbase = kbuf + (size_t)(b * Ts) * CC + h * HD;
  float sc[NT];
  #pragma unroll
  for (int t = 0; t < NT; t++) sc[t] = -3.0e38f;
  float lmax = -3.0e38f;
  for (int t = 0; t < nte; t++) {
    if (t) __syncthreads();
    #pragma unroll
    for (int i = 0; i < 2; i++) {
      int gl = tid + (i << 9);
      int row = gl >> 4, gc = gl & 15;
      ushort4 k4 = *(const ushort4*)(kbase + (size_t)((t << 6) + row) * CC + (gc << 2));
      float4 fv = make_float4(b2f(k4.x), b2f(k4.y), b2f(k4.z), b2f(k4.w));
      *(float4*)((char*)Ks + (((row << 8) + (gc << 4)) ^ ((row & 7) << 4))) = fv;
    }
    __syncthreads();
    float a = 0.f;
    #pragma unroll
    for (int c = 0; c < 16; c++) {
      float4 k4 = *(const float4*)((const char*)Ks + (((lane << 8) + (c << 4)) ^ ((lane & 7) << 4)));
      a += qv[c].x * k4.x + qv[c].y * k4.y + qv[c].z * k4.z + qv[c].w * k4.w;
    }
    int j = (t << 6) + lane;
    if (j < jmax) { sc[t] = a * 0.125f; lmax = fmaxf(lmax, sc[t]); }
  }
  float mx = lmax;
  #pragma unroll
  for (int o = 32; o; o >>= 1) mx = fmaxf(mx, __shfl_xor(mx, o));
  const unsigned short* vrow = vbuf + (size_t)(b * Ts) * CC + h * HD + lane;
  float oacc = 0.f;
  if (TOPK) {
    unsigned key[NT];
    #pragma unroll
    for (int t = 0; t < NT; t++) {
      unsigned u = __float_as_uint(sc[t]);
      key[t] = (u & 0x80000000u) ? ~u : (u | 0x80000000u);
    }
    unsigned prefix = 0u;
    #pragma unroll
    for (int bit = 31; bit >= 0; bit--) {
      unsigned cand = prefix | (1u << bit);
      int cnt = 0;
      #pragma unroll
      for (int t = 0; t < NT; t++)
        cnt += __popcll(__ballot(key[t] >= cand));
      if (cnt >= 64) prefix = cand;
    }
    float psum = 0.f;
    int basec = 0;
    #pragma unroll
    for (int t = 0; t < NT; t++) {
      bool keep = key[t] >= prefix;
      float wv = keep ? exp2f((sc[t] - mx) * 1.4426950408889634f) : 0.f;
      psum += wv;
      unsigned long long mask = __ballot(keep);
      if (keep) {
        int pos = basec + (int)__popcll(mask & ((1ull << lane) - 1ull));
        kidx[wid][pos] = (unsigned short)(lane + (t << 6));
        swt[wid][pos] = wv;
      }
      basec += (int)__popcll(mask);
    }
    #pragma unroll
    for (int o = 32; o; o >>= 1) psum += __shfl_xor(psum, o);
    float inv = 1.0f / psum;
    int nk = basec;
    float a0 = 0.f, a1 = 0.f;
    int i = 0;
    for (; i + 1 < nk; i += 2) {
      a0 += swt[wid][i]     * b2f(vrow[(size_t)kidx[wid][i] * CC]);
      a1 += swt[wid][i + 1] * b2f(vrow[(size_t)kidx[wid][i + 1] * CC]);
    }
    if (i < nk) a0 += swt[wid][i] * b2f(vrow[(size_t)kidx[wid][i] * CC]);
    oacc = (a0 + a1) * inv;
  } else {
    float psum = 0.f;
    #pragma unroll
    for (int t = 0; t < NT; t++) {
      int j = lane + (t << 6);
      float wv = (j < jmax) ? exp2f((sc[t] - mx) * 1.4426950408889634f) : 0.f;
      swt[wid][j] = wv;
      psum += wv;
    }
    #pragma unroll
    for (int o = 32; o; o >>= 1) psum += __shfl_xor(psum, o);
    float inv = 1.0f / psum;
    float a0 = 0.f, a1 = 0.f;
    int j = 0;
    for (; j + 1 < jmax; j += 2) {
      a0 += swt[wid][j]     * b2f(vrow[(size_t)j * CC]);
      a1 += swt[wid][j + 1] * b2f(vrow[(size_t)(j + 1) * CC]);
    }
    if (j < jmax) a0 += swt[wid][j] * b2f(vrow[(size_t)j * CC]);
    oacc = (a0 + a1) * inv;
  }
  yb[(size_t)(b * TT + qi) * CC + h * HD + lane] = bfc(oacc);
}

extern "C" void kernel_launch(void* const* d_in, const int* in_sizes, int n_in,
                              void* d_out, int out_size, void* d_ws, size_t ws_size,
                              hipStream_t stream) {
  const float* id_x    = (const float*)d_in[0];
  const float* id_prev = (const float*)d_in[1];
  const float* frames  = (const float*)d_in[2];
  const float* Wq = (const float*)d_in[3];  const float* bq = (const float*)d_in[4];
  const float* Wk = (const float*)d_in[5];  const float* bk = (const float*)d_in[6];
  const float* Wv = (const float*)d_in[7];  const float* bv = (const float*)d_in[8];
  const float* Wo = (const float*)d_in[9];  const float* bo = (const float*)d_in[10];
  const float* W1 = (const float*)d_in[11]; const float* b1 = (const float*)d_in[12];
  const float* W2 = (const float*)d_in[13]; const float* b2 = (const float*)d_in[14];
  const float* l1g = (const float*)d_in[15]; const float* l1b = (const float*)d_in[16];
  const float* l2g = (const float*)d_in[17]; const float* l2b = (const float*)d_in[18];
  const float* lfg = (const float*)d_in[19]; const float* lfb = (const float*)d_in[20];

  float* x = (float*)d_out;
  char* W  = (char*)d_ws;
  float*          qfb  = (float*)W;                                 // 4MB
  unsigned short* kbuf = (unsigned short*)(W + ((size_t)4  << 20)); // 4MB
  unsigned short* vbuf = (unsigned short*)(W + ((size_t)8  << 20)); // 4MB
  unsigned short* m1b  = (unsigned short*)(W + ((size_t)4  << 20)); // 8MB, alias k+v
  unsigned short* hb   = (unsigned short*)(W + ((size_t)12 << 20)); // 2MB
  unsigned short* ybf  = (unsigned short*)(W + ((size_t)14 << 20)); // 2MB
  unsigned short* xb   = (unsigned short*)(W + ((size_t)16 << 20)); // 2MB
  unsigned short* fb   = (unsigned short*)(W + ((size_t)18 << 20)); // 4MB
  unsigned short* pb   = (unsigned short*)(W + ((size_t)22 << 20)); // 2MB
  unsigned short* wT   = (unsigned short*)(W + ((size_t)24 << 20)); // 6MB or 60MB

  const bool allw = ws_size >= (((size_t)24 << 20) + (size_t)10 * 3145728 * 2);

  prep_k<<<4096, 256, 0, stream>>>(id_x, frames, id_prev, x, fb, pb);
  if (allw)
    transpose_w<<<30720, 256, 0, stream>>>(Wq, Wk, Wv, Wo, W1, W2, 0, wT);

  static const int ssrc[10] = {0, 0, 0, 0, 1, 1, 2, 2, 1, 1};

  for (int i = 0; i < 10; i++) {
    if (!allw)
      transpose_w<<<3072, 256, 0, stream>>>(Wq, Wk, Wv, Wo, W1, W2, i, wT);
    unsigned short* wTl = wT + (allw ? (size_t)i * 3145728 : 0);
    unsigned short* wqT = wTl;
    unsigned short* wkT = wTl + 262144;
    unsigned short* wvT = wTl + 524288;
    unsigned short* woT = wTl + 786432;
    unsigned short* w1T = wTl + 1048576;
    unsigned short* w2T = wTl + 2097152;

    if (i == 0)
      ln_bf<<<2048, 256, 0, stream>>>(x, hb, l1g, l1b);

    // q = LN1(x) @ Wq + bq  (fp32 out for attention)
    gemm_bf<64, 0, 0, 0><<<dim3(8, 32), 256, 0, stream>>>(hb, wqT, bq + i * 512, qfb, nullptr, 2048, 512, 512);

    const unsigned short* kvb; int Mkv;
    if (ssrc[i] == 0)      { kvb = fb; Mkv = 4096; }
    else if (ssrc[i] == 1) { kvb = xb; Mkv = 2048; }
    else                   { kvb = pb; Mkv = 2048; }
    if (Mkv == 4096) {
      gemm_bf<128, 0, 0, 1><<<dim3(8, 32), 256, 0, stream>>>(kvb, wkT, bk + i * 512, kbuf, nullptr, 4096, 512, 512);
      gemm_bf<128, 0, 0, 1><<<dim3(8, 32), 256, 0, stream>>>(kvb, wvT, bv + i * 512, vbuf, nullptr, 4096, 512, 512);
    } else {
      gemm_bf<64, 0, 0, 1><<<dim3(8, 32), 256, 0, stream>>>(kvb, wkT, bk + i * 512, kbuf, nullptr, 2048, 512, 512);
      gemm_bf<64, 0, 0, 1><<<dim3(8, 32), 256, 0, stream>>>(kvb, wvT, bv + i * 512, vbuf, nullptr, 2048, 512, 512);
    }

    if (ssrc[i] == 0)      attn_k<0, 1, 8><<<2048, 512, 0, stream>>>(qfb, kbuf, vbuf, ybf);
    else if (ssrc[i] == 1) attn_k<1, 0, 4><<<2048, 512, 0, stream>>>(qfb, kbuf, vbuf, ybf);
    else                   attn_k<0, 0, 4><<<2048, 512, 0, stream>>>(qfb, kbuf, vbuf, ybf);

    // x = x + y @ Wo + bo
    gemm_bf<64, 0, 1, 0><<<dim3(8, 32), 256, 0, stream>>>(ybf, woT, bo + i * 512, x, x, 2048, 512, 512);
    // h = LN2(x) bf16
    ln_bf<<<2048, 256, 0, stream>>>(x, hb, l2g + i * 512, l2b + i * 512);
    // m1 = gelu(h @ W1 + b1) bf16
    gemm_bf<128, 1, 0, 1><<<dim3(32, 16), 256, 0, stream>>>(hb, w1T, b1 + i * 2048, m1b, nullptr, 2048, 2048, 512);
    // x = x + m1 @ W2 + b2
    gemm_bf<64, 0, 1, 0><<<dim3(8, 32), 256, 0, stream>>>(m1b, w2T, b2 + i * 512, x, x, 2048, 512, 2048);

    if (i < 9)
      ln_chain<<<2048, 256, 0, stream>>>(x, x, xb, lfg + i * 512, lfb + i * 512,
                                         l1g + (i + 1) * 512, l1b + (i + 1) * 512, hb);
    else
      ln_final<<<2048, 256, 0, stream>>>(x, x, lfg + i * 512, lfb + i * 512);
  }
}

// Round 6
// 1404.727 us; speedup vs baseline: 4.8627x; 1.2041x over previous
//
#include <hip/hip_runtime.h>
#include <math.h>

#define CC 512
#define NH 8
#define HD 64
#define TT 256

typedef __attribute__((ext_vector_type(8))) short short8v;
typedef __attribute__((ext_vector_type(4))) float f32x4;

__device__ inline unsigned short bfc(float f) {  // fp32 -> bf16, RNE
  unsigned u = __float_as_uint(f);
  return (unsigned short)((u + 0x7fffu + ((u >> 16) & 1u)) >> 16);
}
__device__ inline float b2f(unsigned short s) {
  return __uint_as_float((unsigned)s << 16);
}

// ---------------- prep: x=id_x; fb=bf16(frames); pb=bf16(id_prev) ------------
__global__ __launch_bounds__(256) void prep_k(const float* __restrict__ id_x,
    const float* __restrict__ frames, const float* __restrict__ id_prev,
    float* __restrict__ x, unsigned short* __restrict__ fb,
    unsigned short* __restrict__ pb) {
  int i = blockIdx.x * 256 + threadIdx.x;  // 0..1048575
  if (i < 262144) {
    ((float4*)x)[i] = ((const float4*)id_x)[i];
  } else if (i < 786432) {
    int j = i - 262144;
    float4 f = ((const float4*)frames)[j];
    ushort4 o; o.x = bfc(f.x); o.y = bfc(f.y); o.z = bfc(f.z); o.w = bfc(f.w);
    ((ushort4*)fb)[j] = o;
  } else {
    int j = i - 786432;
    float4 f = ((const float4*)id_prev)[j];
    ushort4 o; o.x = bfc(f.x); o.y = bfc(f.y); o.z = bfc(f.z); o.w = bfc(f.w);
    ((ushort4*)pb)[j] = o;
  }
}

// ---------------- LayerNorm variants ----------------
__global__ __launch_bounds__(256) void ln_bf(const float* __restrict__ in,
    unsigned short* __restrict__ out, const float* __restrict__ g, const float* __restrict__ b) {
  int row = blockIdx.x, t = threadIdx.x;
  const float* r = in + (size_t)row * CC;
  float v0 = r[t], v1 = r[t + 256];
  float s = v0 + v1;
  #pragma unroll
  for (int o = 32; o; o >>= 1) s += __shfl_xor(s, o);
  __shared__ float r1[4], r2[4];
  if ((t & 63) == 0) r1[t >> 6] = s;
  __syncthreads();
  float mu = (r1[0] + r1[1] + r1[2] + r1[3]) * (1.0f / CC);
  float d0 = v0 - mu, d1 = v1 - mu;
  float sq = d0 * d0 + d1 * d1;
  #pragma unroll
  for (int o = 32; o; o >>= 1) sq += __shfl_xor(sq, o);
  if ((t & 63) == 0) r2[t >> 6] = sq;
  __syncthreads();
  float inv = rsqrtf((r2[0] + r2[1] + r2[2] + r2[3]) * (1.0f / CC) + 1e-5f);
  out[(size_t)row * CC + t]       = bfc(d0 * inv * g[t] + b[t]);
  out[(size_t)row * CC + t + 256] = bfc(d1 * inv * g[t + 256] + b[t + 256]);
}

__global__ __launch_bounds__(256) void ln_final(const float* __restrict__ in,
    float* __restrict__ out, const float* __restrict__ g, const float* __restrict__ b) {
  int row = blockIdx.x, t = threadIdx.x;
  const float* r = in + (size_t)row * CC;
  float v0 = r[t], v1 = r[t + 256];
  float s = v0 + v1;
  #pragma unroll
  for (int o = 32; o; o >>= 1) s += __shfl_xor(s, o);
  __shared__ float r1[4], r2[4];
  if ((t & 63) == 0) r1[t >> 6] = s;
  __syncthreads();
  float mu = (r1[0] + r1[1] + r1[2] + r1[3]) * (1.0f / CC);
  float d0 = v0 - mu, d1 = v1 - mu;
  float sq = d0 * d0 + d1 * d1;
  #pragma unroll
  for (int o = 32; o; o >>= 1) sq += __shfl_xor(sq, o);
  if ((t & 63) == 0) r2[t >> 6] = sq;
  __syncthreads();
  float inv = rsqrtf((r2[0] + r2[1] + r2[2] + r2[3]) * (1.0f / CC) + 1e-5f);
  out[(size_t)row * CC + t]       = d0 * inv * g[t] + b[t];
  out[(size_t)row * CC + t + 256] = d1 * inv * g[t + 256] + b[t + 256];
}

// LNf then LN1-of-next-layer: writes x fp32, xb bf16, h bf16
__global__ __launch_bounds__(256) void ln_chain(const float* __restrict__ in,
    float* __restrict__ xout, unsigned short* __restrict__ xb,
    const float* __restrict__ gf, const float* __restrict__ bf,
    const float* __restrict__ g1, const float* __restrict__ b1,
    unsigned short* __restrict__ hout) {
  int row = blockIdx.x, t = threadIdx.x;
  const float* r = in + (size_t)row * CC;
  float v0 = r[t], v1 = r[t + 256];
  float s = v0 + v1;
  #pragma unroll
  for (int o = 32; o; o >>= 1) s += __shfl_xor(s, o);
  __shared__ float r1[4], r2[4];
  if ((t & 63) == 0) r1[t >> 6] = s;
  __syncthreads();
  float mu = (r1[0] + r1[1] + r1[2] + r1[3]) * (1.0f / CC);
  float d0 = v0 - mu, d1 = v1 - mu;
  float sq = d0 * d0 + d1 * d1;
  #pragma unroll
  for (int o = 32; o; o >>= 1) sq += __shfl_xor(sq, o);
  if ((t & 63) == 0) r2[t >> 6] = sq;
  __syncthreads();
  float inv = rsqrtf((r2[0] + r2[1] + r2[2] + r2[3]) * (1.0f / CC) + 1e-5f);
  float xf0 = d0 * inv * gf[t] + bf[t];
  float xf1 = d1 * inv * gf[t + 256] + bf[t + 256];
  xout[(size_t)row * CC + t]       = xf0;
  xout[(size_t)row * CC + t + 256] = xf1;
  xb[(size_t)row * CC + t]         = bfc(xf0);
  xb[(size_t)row * CC + t + 256]   = bfc(xf1);
  __syncthreads();
  float s2 = xf0 + xf1;
  #pragma unroll
  for (int o = 32; o; o >>= 1) s2 += __shfl_xor(s2, o);
  if ((t & 63) == 0) r1[t >> 6] = s2;
  __syncthreads();
  float mu2 = (r1[0] + r1[1] + r1[2] + r1[3]) * (1.0f / CC);
  float e0 = xf0 - mu2, e1 = xf1 - mu2;
  float sq2 = e0 * e0 + e1 * e1;
  #pragma unroll
  for (int o = 32; o; o >>= 1) sq2 += __shfl_xor(sq2, o);
  if ((t & 63) == 0) r2[t >> 6] = sq2;
  __syncthreads();
  float inv2 = rsqrtf((r2[0] + r2[1] + r2[2] + r2[3]) * (1.0f / CC) + 1e-5f);
  hout[(size_t)row * CC + t]       = bfc(e0 * inv2 * g1[t] + b1[t]);
  hout[(size_t)row * CC + t + 256] = bfc(e1 * inv2 * g1[t + 256] + b1[t + 256]);
}

// ---------------- weight transpose+convert: W[K][N] fp32 -> WT[N][K] bf16 -----
__global__ __launch_bounds__(256) void transpose_w(
    const float* __restrict__ Wq, const float* __restrict__ Wk,
    const float* __restrict__ Wv, const float* __restrict__ Wo,
    const float* __restrict__ W1, const float* __restrict__ W2,
    int layer_base, unsigned short* __restrict__ wT) {
  int lz = blockIdx.x / 3072;
  int layer = layer_base + lz;
  int bid = blockIdx.x - lz * 3072;
  unsigned short* wTl = wT + (size_t)lz * 3145728;
  const float* src; unsigned short* dst; int R, Cn, tile, lg;
  if (bid < 1024) {
    int seg = bid >> 8; tile = bid & 255; R = 512; Cn = 512; lg = 4;
    const float* s4[4] = {Wq, Wk, Wv, Wo};
    src = s4[seg] + (size_t)layer * 262144;
    dst = wTl + (size_t)seg * 262144;
  } else if (bid < 2048) {
    tile = bid - 1024; R = 512; Cn = 2048; lg = 6;
    src = W1 + (size_t)layer * 1048576; dst = wTl + 1048576;
  } else {
    tile = bid - 2048; R = 2048; Cn = 512; lg = 4;
    src = W2 + (size_t)layer * 1048576; dst = wTl + 2097152;
  }
  int trb = tile >> lg, tcb = tile & ((1 << lg) - 1);
  __shared__ float tl[32][33];
  int t = threadIdx.x;
  int r = t >> 3, c4 = (t & 7) << 2;
  const float* sp = src + (size_t)(trb * 32 + r) * Cn + tcb * 32 + c4;
  float4 fv = *(const float4*)sp;
  tl[r][c4] = fv.x; tl[r][c4 + 1] = fv.y; tl[r][c4 + 2] = fv.z; tl[r][c4 + 3] = fv.w;
  __syncthreads();
  unsigned short* dp = dst + (size_t)(tcb * 32 + r) * R + trb * 32 + c4;
  ushort4 ov;
  ov.x = bfc(tl[c4][r]); ov.y = bfc(tl[c4 + 1][r]);
  ov.z = bfc(tl[c4 + 2][r]); ov.w = bfc(tl[c4 + 3][r]);
  *(ushort4*)dp = ov;
}

// ---------------- bf16 MFMA GEMM (unchanged, proven) -------------------------
template<int BM, int GELU, int RES, int OUTBF>
__global__ __launch_bounds__(256) void gemm_bf(
    const unsigned short* __restrict__ A, const unsigned short* __restrict__ WT,
    const float* __restrict__ bias, void* __restrict__ outp,
    const float* __restrict__ res, int M, int N, int K) {
  __shared__ unsigned short As[BM * 64];
  __shared__ unsigned short Bs[64 * 64];
  const int tid = threadIdx.x, lane = tid & 63, wid = tid >> 6;
  const int bm = blockIdx.y * BM, bn = blockIdx.x << 6;
  const int wm = (wid >> 1) * (BM / 2), wn = (wid & 1) << 5;
  constexpr int MF = BM / 32;
  f32x4 acc[MF][2] = {};
  const int fr = lane & 15, fq = lane >> 4;
  for (int k0 = 0; k0 < K; k0 += 64) {
    if (k0) __syncthreads();
    #pragma unroll
    for (int i = 0; i < BM / 32; i++) {
      int gl = tid + (i << 8);
      int row = gl >> 3, gc = gl & 7;
      short8v d = *(const short8v*)(A + (size_t)(bm + row) * K + k0 + (gc << 3));
      *(short8v*)((char*)As + ((((row << 7) + (gc << 4))) ^ ((row & 7) << 4))) = d;
    }
    #pragma unroll
    for (int i = 0; i < 2; i++) {
      int gl = tid + (i << 8);
      int row = gl >> 3, gc = gl & 7;
      short8v d = *(const short8v*)(WT + (size_t)(bn + row) * K + k0 + (gc << 3));
      *(short8v*)((char*)Bs + ((((row << 7) + (gc << 4))) ^ ((row & 7) << 4))) = d;
    }
    __syncthreads();
    short8v af[MF][2], bf2[2][2];
    #pragma unroll
    for (int mf = 0; mf < MF; mf++)
      #pragma unroll
      for (int ks = 0; ks < 2; ks++) {
        int r = wm + mf * 16 + fr;
        int c = (ks << 2) + fq;
        af[mf][ks] = *(const short8v*)((const char*)As + ((((r << 7) + (c << 4))) ^ ((r & 7) << 4)));
      }
    #pragma unroll
    for (int nf = 0; nf < 2; nf++)
      #pragma unroll
      for (int ks = 0; ks < 2; ks++) {
        int r = wn + nf * 16 + fr;
        int c = (ks << 2) + fq;
        bf2[nf][ks] = *(const short8v*)((const char*)Bs + ((((r << 7) + (c << 4))) ^ ((r & 7) << 4)));
      }
    #pragma unroll
    for (int mf = 0; mf < MF; mf++)
      #pragma unroll
      for (int nf = 0; nf < 2; nf++) {
        acc[mf][nf] = __builtin_amdgcn_mfma_f32_16x16x32_bf16(af[mf][0], bf2[nf][0], acc[mf][nf], 0, 0, 0);
        acc[mf][nf] = __builtin_amdgcn_mfma_f32_16x16x32_bf16(af[mf][1], bf2[nf][1], acc[mf][nf], 0, 0, 0);
      }
  }
  #pragma unroll
  for (int mf = 0; mf < MF; mf++)
    #pragma unroll
    for (int nf = 0; nf < 2; nf++) {
      int col = bn + wn + nf * 16 + fr;
      float bia = bias[col];
      #pragma unroll
      for (int rr = 0; rr < 4; rr++) {
        int row = bm + wm + mf * 16 + fq * 4 + rr;
        float vv = acc[mf][nf][rr] + bia;
        if (GELU) vv = 0.5f * vv * (1.0f + erff(vv * 0.70710678118654752f));
        if (RES)  vv += res[(size_t)row * N + col];
        if (OUTBF) ((unsigned short*)outp)[(size_t)row * N + col] = bfc(vv);
        else       ((float*)outp)[(size_t)row * N + col] = vv;
      }
    }
}

// ---------------- MFMA attention --------------------------------------------
// Block = 4 waves = 16 q-rows of one (b,h). QK^T via mfma_16x16x32_bf16 into
// LDS scores S[16][TSK+8] fp32; per-wave 4 rows: radix-select top-64 / softmax
// (lane=key layout); PV = coalesced bf16 V gather (compact kidx for topk).
template<int CAUSAL, int TOPK, int TSK>
__global__ __launch_bounds__(256) void attn_m(
    const float* __restrict__ qf, const unsigned short* __restrict__ kbuf,
    const unsigned short* __restrict__ vbuf, unsigned short* __restrict__ yb) {
  constexpr int NT = TSK / 64;
  constexpr int NKC = TSK / 128;
  constexpr int SST = TSK + 8;           // stride mod 32 = 8 -> spread banks
  __shared__ float S[16 * SST];
  __shared__ unsigned short Ks[128 * 64];  // 16KB, XOR-swizzled
  __shared__ unsigned short Qs[16 * 64];   // 2KB, XOR-swizzled
  __shared__ float swt[TOPK ? 16 : 1][TOPK ? 128 : 1];
  __shared__ unsigned short kidx[TOPK ? 16 : 1][TOPK ? 128 : 1];
  int tid = threadIdx.x, lane = tid & 63, wid = tid >> 6;
  int bid = blockIdx.x;
  int swz = ((bid & 7) << 7) | (bid >> 3);  // 1024 blocks, bijective XCD swizzle
  int b = swz >> 7, h = (swz >> 4) & 7, qt = swz & 15;
  int q0 = qt << 4;
  // ---- stage Q (pre-scaled by 1/8) ----
  {
    int row = tid >> 4, c4 = (tid & 15) << 2;
    float4 qv = *(const float4*)(qf + (size_t)((b << 8) + q0 + row) * CC + (h << 6) + c4);
    ushort4 o;
    o.x = bfc(qv.x * 0.125f); o.y = bfc(qv.y * 0.125f);
    o.z = bfc(qv.z * 0.125f); o.w = bfc(qv.w * 0.125f);
    int off = (row << 7) + (c4 << 1);
    *(ushort4*)((char*)Qs + (off ^ ((row & 7) << 4))) = o;
  }
  __syncthreads();
  short8v aF[2];
  {
    int r = lane & 15, kq = lane >> 4;
    #pragma unroll
    for (int kc2 = 0; kc2 < 2; kc2++)
      aF[kc2] = *(const short8v*)((const char*)Qs +
                 (((r << 7) + (kc2 << 6) + (kq << 4)) ^ ((r & 7) << 4)));
  }
  int nte = NKC;
  if (CAUSAL) { int ub = (q0 + 16 + 127) >> 7; nte = ub < NKC ? ub : NKC; }
  const unsigned short* kgb = kbuf + (size_t)b * TSK * CC + (h << 6);
  for (int t = 0; t < nte; t++) {
    __syncthreads();
    {  // stage K tile: 128 keys x 64 dims bf16, swizzled
      int row = tid & 127, seg = tid >> 7;
      const unsigned short* src = kgb + (size_t)((t << 7) + row) * CC + (seg << 5);
      #pragma unroll
      for (int j = 0; j < 4; j++) {
        short8v d = *(const short8v*)(src + (j << 3));
        int slot = (seg << 2) + j;
        *(short8v*)((char*)Ks + (((row << 7) + (slot << 4)) ^ ((row & 7) << 4))) = d;
      }
    }
    __syncthreads();
    int kq = lane >> 4;
    #pragma unroll
    for (int f = 0; f < 2; f++) {
      f32x4 acc = {};
      int key16 = (wid << 5) + (f << 4) + (lane & 15);
      #pragma unroll
      for (int kc2 = 0; kc2 < 2; kc2++) {
        short8v bF = *(const short8v*)((const char*)Ks +
                      (((key16 << 7) + (kc2 << 6) + (kq << 4)) ^ ((key16 & 7) << 4)));
        acc = __builtin_amdgcn_mfma_f32_16x16x32_bf16(aF[kc2], bF, acc, 0, 0, 0);
      }
      int col = (t << 7) + key16;
      #pragma unroll
      for (int r = 0; r < 4; r++)
        S[(kq * 4 + r) * SST + col] = acc[r];
    }
  }
  __syncthreads();
  // ---- per-wave: 4 rows select/softmax + PV gather ----
  const unsigned short* vgb = vbuf + (size_t)b * TSK * CC + (h << 6) + lane;
  for (int rr = 0; rr < 4; rr++) {
    int row = (wid << 2) + rr;
    int qi = q0 + row;
    int jmax = CAUSAL ? (qi + 1) : TSK;
    float sc[NT];
    float lmax = -3.0e38f;
    #pragma unroll
    for (int tt = 0; tt < NT; tt++) {
      int key = lane + (tt << 6);
      float v = (!CAUSAL || key < jmax) ? S[row * SST + key] : -3.0e38f;
      sc[tt] = v;
      lmax = fmaxf(lmax, v);
    }
    float mx = lmax;
    #pragma unroll
    for (int o = 32; o; o >>= 1) mx = fmaxf(mx, __shfl_xor(mx, o));
    float oacc = 0.f;
    if (TOPK) {
      unsigned key[NT];
      #pragma unroll
      for (int tt = 0; tt < NT; tt++) {
        unsigned u = __float_as_uint(sc[tt]);
        key[tt] = (u & 0x80000000u) ? ~u : (u | 0x80000000u);
      }
      unsigned prefix = 0u;
      #pragma unroll
      for (int bit = 31; bit >= 0; bit--) {
        unsigned cand = prefix | (1u << bit);
        int cnt = 0;
        #pragma unroll
        for (int tt = 0; tt < NT; tt++)
          cnt += __popcll(__ballot(key[tt] >= cand));
        if (cnt >= 64) prefix = cand;
      }
      float wvv[NT];
      float psum = 0.f;
      int basec = 0;
      #pragma unroll
      for (int tt = 0; tt < NT; tt++) {
        bool keep = key[tt] >= prefix;
        float wv = keep ? exp2f((sc[tt] - mx) * 1.4426950408889634f) : 0.f;
        wvv[tt] = wv;
        psum += wv;
        unsigned long long mask = __ballot(keep);
        if (keep) {
          int pos = basec + (int)__popcll(mask & ((1ull << lane) - 1ull));
          if (pos < 128) {
            kidx[row][pos] = (unsigned short)(lane + (tt << 6));
            swt[row][pos] = wv;
          }
        }
        basec += (int)__popcll(mask);
      }
      #pragma unroll
      for (int o = 32; o; o >>= 1) psum += __shfl_xor(psum, o);
      float inv = 1.0f / psum;
      int nk = basec;
      if (nk <= 128) {
        float a0 = 0.f, a1 = 0.f;
        int i = 0;
        for (; i + 1 < nk; i += 2) {
          a0 += swt[row][i]     * b2f(vgb[(size_t)kidx[row][i] * CC]);
          a1 += swt[row][i + 1] * b2f(vgb[(size_t)kidx[row][i + 1] * CC]);
        }
        if (i < nk) a0 += swt[row][i] * b2f(vgb[(size_t)kidx[row][i] * CC]);
        oacc = (a0 + a1) * inv;
      } else {  // pathological tie overflow: full scan via S
        #pragma unroll
        for (int tt = 0; tt < NT; tt++)
          S[row * SST + lane + (tt << 6)] = wvv[tt];
        float a0 = 0.f, a1 = 0.f;
        for (int j = 0; j + 1 < TSK; j += 2) {
          a0 += S[row * SST + j]     * b2f(vgb[(size_t)j * CC]);
          a1 += S[row * SST + j + 1] * b2f(vgb[(size_t)(j + 1) * CC]);
        }
        oacc = (a0 + a1) * inv;
      }
    } else {
      float psum = 0.f;
      #pragma unroll
      for (int tt = 0; tt < NT; tt++) {
        int keyj = lane + (tt << 6);
        float wv = (keyj < jmax) ? exp2f((sc[tt] - mx) * 1.4426950408889634f) : 0.f;
        S[row * SST + keyj] = wv;
        psum += wv;
      }
      #pragma unroll
      for (int o = 32; o; o >>= 1) psum += __shfl_xor(psum, o);
      float inv = 1.0f / psum;
      float a0 = 0.f, a1 = 0.f;
      int j = 0;
      for (; j + 1 < jmax; j += 2) {
        a0 += S[row * SST + j]     * b2f(vgb[(size_t)j * CC]);
        a1 += S[row * SST + j + 1] * b2f(vgb[(size_t)(j + 1) * CC]);
      }
      if (j < jmax) a0 += S[row * SST + j] * b2f(vgb[(size_t)j * CC]);
      oacc = (a0 + a1) * inv;
    }
    yb[(size_t)((b << 8) + qi) * CC + (h << 6) + lane] = bfc(oacc);
  }
}

extern "C" void kernel_launch(void* const* d_in, const int* in_sizes, int n_in,
                              void* d_out, int out_size, void* d_ws, size_t ws_size,
                              hipStream_t stream) {
  const float* id_x    = (const float*)d_in[0];
  const float* id_prev = (const float*)d_in[1];
  const float* frames  = (const float*)d_in[2];
  const float* Wq = (const float*)d_in[3];  const float* bq = (const float*)d_in[4];
  const float* Wk = (const float*)d_in[5];  const float* bk = (const float*)d_in[6];
  const float* Wv = (const float*)d_in[7];  const float* bv = (const float*)d_in[8];
  const float* Wo = (const float*)d_in[9];  const float* bo = (const float*)d_in[10];
  const float* W1 = (const float*)d_in[11]; const float* b1 = (const float*)d_in[12];
  const float* W2 = (const float*)d_in[13]; const float* b2 = (const float*)d_in[14];
  const float* l1g = (const float*)d_in[15]; const float* l1b = (const float*)d_in[16];
  const float* l2g = (const float*)d_in[17]; const float* l2b = (const float*)d_in[18];
  const float* lfg = (const float*)d_in[19]; const float* lfb = (const float*)d_in[20];

  float* x = (float*)d_out;
  char* W  = (char*)d_ws;
  float*          qfb  = (float*)W;                                 // 4MB
  unsigned short* kbuf = (unsigned short*)(W + ((size_t)4  << 20)); // 4MB
  unsigned short* vbuf = (unsigned short*)(W + ((size_t)8  << 20)); // 4MB
  unsigned short* m1b  = (unsigned short*)(W + ((size_t)4  << 20)); // 8MB, alias k+v
  unsigned short* hb   = (unsigned short*)(W + ((size_t)12 << 20)); // 2MB
  unsigned short* ybf  = (unsigned short*)(W + ((size_t)14 << 20)); // 2MB
  unsigned short* xb   = (unsigned short*)(W + ((size_t)16 << 20)); // 2MB
  unsigned short* fb   = (unsigned short*)(W + ((size_t)18 << 20)); // 4MB
  unsigned short* pb   = (unsigned short*)(W + ((size_t)22 << 20)); // 2MB
  unsigned short* wT   = (unsigned short*)(W + ((size_t)24 << 20)); // 6MB or 60MB

  const bool allw = ws_size >= (((size_t)24 << 20) + (size_t)10 * 3145728 * 2);

  prep_k<<<4096, 256, 0, stream>>>(id_x, frames, id_prev, x, fb, pb);
  if (allw)
    transpose_w<<<30720, 256, 0, stream>>>(Wq, Wk, Wv, Wo, W1, W2, 0, wT);

  static const int ssrc[10] = {0, 0, 0, 0, 1, 1, 2, 2, 1, 1};

  for (int i = 0; i < 10; i++) {
    if (!allw)
      transpose_w<<<3072, 256, 0, stream>>>(Wq, Wk, Wv, Wo, W1, W2, i, wT);
    unsigned short* wTl = wT + (allw ? (size_t)i * 3145728 : 0);
    unsigned short* wqT = wTl;
    unsigned short* wkT = wTl + 262144;
    unsigned short* wvT = wTl + 524288;
    unsigned short* woT = wTl + 786432;
    unsigned short* w1T = wTl + 1048576;
    unsigned short* w2T = wTl + 2097152;

    if (i == 0)
      ln_bf<<<2048, 256, 0, stream>>>(x, hb, l1g, l1b);

    gemm_bf<64, 0, 0, 0><<<dim3(8, 32), 256, 0, stream>>>(hb, wqT, bq + i * 512, qfb, nullptr, 2048, 512, 512);

    const unsigned short* kvb; int Mkv;
    if (ssrc[i] == 0)      { kvb = fb; Mkv = 4096; }
    else if (ssrc[i] == 1) { kvb = xb; Mkv = 2048; }
    else                   { kvb = pb; Mkv = 2048; }
    if (Mkv == 4096) {
      gemm_bf<128, 0, 0, 1><<<dim3(8, 32), 256, 0, stream>>>(kvb, wkT, bk + i * 512, kbuf, nullptr, 4096, 512, 512);
      gemm_bf<128, 0, 0, 1><<<dim3(8, 32), 256, 0, stream>>>(kvb, wvT, bv + i * 512, vbuf, nullptr, 4096, 512, 512);
    } else {
      gemm_bf<64, 0, 0, 1><<<dim3(8, 32), 256, 0, stream>>>(kvb, wkT, bk + i * 512, kbuf, nullptr, 2048, 512, 512);
      gemm_bf<64, 0, 0, 1><<<dim3(8, 32), 256, 0, stream>>>(kvb, wvT, bv + i * 512, vbuf, nullptr, 2048, 512, 512);
    }

    if (ssrc[i] == 0)      attn_m<0, 1, 512><<<1024, 256, 0, stream>>>(qfb, kbuf, vbuf, ybf);
    else if (ssrc[i] == 1) attn_m<1, 0, 256><<<1024, 256, 0, stream>>>(qfb, kbuf, vbuf, ybf);
    else                   attn_m<0, 0, 256><<<1024, 256, 0, stream>>>(qfb, kbuf, vbuf, ybf);

    gemm_bf<64, 0, 1, 0><<<dim3(8, 32), 256, 0, stream>>>(ybf, woT, bo + i * 512, x, x, 2048, 512, 512);
    ln_bf<<<2048, 256, 0, stream>>>(x, hb, l2g + i * 512, l2b + i * 512);
    gemm_bf<128, 1, 0, 1><<<dim3(32, 16), 256, 0, stream>>>(hb, w1T, b1 + i * 2048, m1b, nullptr, 2048, 2048, 512);
    gemm_bf<64, 0, 1, 0><<<dim3(8, 32), 256, 0, stream>>>(m1b, w2T, b2 + i * 512, x, x, 2048, 512, 2048);

    if (i < 9)
      ln_chain<<<2048, 256, 0, stream>>>(x, x, xb, lfg + i * 512, lfb + i * 512,
                                         l1g + (i + 1) * 512, l1b + (i + 1) * 512, hb);
    else
      ln_final<<<2048, 256, 0, stream>>>(x, x, lfg + i * 512, lfb + i * 512);
  }
}

// Round 7
// 1186.894 us; speedup vs baseline: 5.7551x; 1.1835x over previous
//
#include <hip/hip_runtime.h>
#include <math.h>

#define CC 512
#define NH 8
#define HD 64
#define TT 256

typedef __attribute__((ext_vector_type(8))) short short8v;
typedef __attribute__((ext_vector_type(4))) float f32x4;

__device__ inline unsigned short bfc(float f) {  // fp32 -> bf16, RNE
  unsigned u = __float_as_uint(f);
  return (unsigned short)((u + 0x7fffu + ((u >> 16) & 1u)) >> 16);
}
__device__ inline float b2f(unsigned short s) {
  return __uint_as_float((unsigned)s << 16);
}

// ---------------- prep: x=id_x; fb=bf16(frames); pb=bf16(id_prev) ------------
__global__ __launch_bounds__(256) void prep_k(const float* __restrict__ id_x,
    const float* __restrict__ frames, const float* __restrict__ id_prev,
    float* __restrict__ x, unsigned short* __restrict__ fb,
    unsigned short* __restrict__ pb) {
  int i = blockIdx.x * 256 + threadIdx.x;  // 0..1048575
  if (i < 262144) {
    ((float4*)x)[i] = ((const float4*)id_x)[i];
  } else if (i < 786432) {
    int j = i - 262144;
    float4 f = ((const float4*)frames)[j];
    ushort4 o; o.x = bfc(f.x); o.y = bfc(f.y); o.z = bfc(f.z); o.w = bfc(f.w);
    ((ushort4*)fb)[j] = o;
  } else {
    int j = i - 786432;
    float4 f = ((const float4*)id_prev)[j];
    ushort4 o; o.x = bfc(f.x); o.y = bfc(f.y); o.z = bfc(f.z); o.w = bfc(f.w);
    ((ushort4*)pb)[j] = o;
  }
}

// ---------------- LayerNorm variants ----------------
__global__ __launch_bounds__(256) void ln_bf(const float* __restrict__ in,
    unsigned short* __restrict__ out, const float* __restrict__ g, const float* __restrict__ b) {
  int row = blockIdx.x, t = threadIdx.x;
  const float* r = in + (size_t)row * CC;
  float v0 = r[t], v1 = r[t + 256];
  float s = v0 + v1;
  #pragma unroll
  for (int o = 32; o; o >>= 1) s += __shfl_xor(s, o);
  __shared__ float r1[4], r2[4];
  if ((t & 63) == 0) r1[t >> 6] = s;
  __syncthreads();
  float mu = (r1[0] + r1[1] + r1[2] + r1[3]) * (1.0f / CC);
  float d0 = v0 - mu, d1 = v1 - mu;
  float sq = d0 * d0 + d1 * d1;
  #pragma unroll
  for (int o = 32; o; o >>= 1) sq += __shfl_xor(sq, o);
  if ((t & 63) == 0) r2[t >> 6] = sq;
  __syncthreads();
  float inv = rsqrtf((r2[0] + r2[1] + r2[2] + r2[3]) * (1.0f / CC) + 1e-5f);
  out[(size_t)row * CC + t]       = bfc(d0 * inv * g[t] + b[t]);
  out[(size_t)row * CC + t + 256] = bfc(d1 * inv * g[t + 256] + b[t + 256]);
}

__global__ __launch_bounds__(256) void ln_final(const float* __restrict__ in,
    float* __restrict__ out, const float* __restrict__ g, const float* __restrict__ b) {
  int row = blockIdx.x, t = threadIdx.x;
  const float* r = in + (size_t)row * CC;
  float v0 = r[t], v1 = r[t + 256];
  float s = v0 + v1;
  #pragma unroll
  for (int o = 32; o; o >>= 1) s += __shfl_xor(s, o);
  __shared__ float r1[4], r2[4];
  if ((t & 63) == 0) r1[t >> 6] = s;
  __syncthreads();
  float mu = (r1[0] + r1[1] + r1[2] + r1[3]) * (1.0f / CC);
  float d0 = v0 - mu, d1 = v1 - mu;
  float sq = d0 * d0 + d1 * d1;
  #pragma unroll
  for (int o = 32; o; o >>= 1) sq += __shfl_xor(sq, o);
  if ((t & 63) == 0) r2[t >> 6] = sq;
  __syncthreads();
  float inv = rsqrtf((r2[0] + r2[1] + r2[2] + r2[3]) * (1.0f / CC) + 1e-5f);
  out[(size_t)row * CC + t]       = d0 * inv * g[t] + b[t];
  out[(size_t)row * CC + t + 256] = d1 * inv * g[t + 256] + b[t + 256];
}

// LNf then LN1-of-next-layer: writes x fp32, xb bf16, h bf16
__global__ __launch_bounds__(256) void ln_chain(const float* __restrict__ in,
    float* __restrict__ xout, unsigned short* __restrict__ xb,
    const float* __restrict__ gf, const float* __restrict__ bf,
    const float* __restrict__ g1, const float* __restrict__ b1,
    unsigned short* __restrict__ hout) {
  int row = blockIdx.x, t = threadIdx.x;
  const float* r = in + (size_t)row * CC;
  float v0 = r[t], v1 = r[t + 256];
  float s = v0 + v1;
  #pragma unroll
  for (int o = 32; o; o >>= 1) s += __shfl_xor(s, o);
  __shared__ float r1[4], r2[4];
  if ((t & 63) == 0) r1[t >> 6] = s;
  __syncthreads();
  float mu = (r1[0] + r1[1] + r1[2] + r1[3]) * (1.0f / CC);
  float d0 = v0 - mu, d1 = v1 - mu;
  float sq = d0 * d0 + d1 * d1;
  #pragma unroll
  for (int o = 32; o; o >>= 1) sq += __shfl_xor(sq, o);
  if ((t & 63) == 0) r2[t >> 6] = sq;
  __syncthreads();
  float inv = rsqrtf((r2[0] + r2[1] + r2[2] + r2[3]) * (1.0f / CC) + 1e-5f);
  float xf0 = d0 * inv * gf[t] + bf[t];
  float xf1 = d1 * inv * gf[t + 256] + bf[t + 256];
  xout[(size_t)row * CC + t]       = xf0;
  xout[(size_t)row * CC + t + 256] = xf1;
  xb[(size_t)row * CC + t]         = bfc(xf0);
  xb[(size_t)row * CC + t + 256]   = bfc(xf1);
  __syncthreads();
  float s2 = xf0 + xf1;
  #pragma unroll
  for (int o = 32; o; o >>= 1) s2 += __shfl_xor(s2, o);
  if ((t & 63) == 0) r1[t >> 6] = s2;
  __syncthreads();
  float mu2 = (r1[0] + r1[1] + r1[2] + r1[3]) * (1.0f / CC);
  float e0 = xf0 - mu2, e1 = xf1 - mu2;
  float sq2 = e0 * e0 + e1 * e1;
  #pragma unroll
  for (int o = 32; o; o >>= 1) sq2 += __shfl_xor(sq2, o);
  if ((t & 63) == 0) r2[t >> 6] = sq2;
  __syncthreads();
  float inv2 = rsqrtf((r2[0] + r2[1] + r2[2] + r2[3]) * (1.0f / CC) + 1e-5f);
  hout[(size_t)row * CC + t]       = bfc(e0 * inv2 * g1[t] + b1[t]);
  hout[(size_t)row * CC + t + 256] = bfc(e1 * inv2 * g1[t + 256] + b1[t + 256]);
}

// ---------------- weight transpose+convert: W[K][N] fp32 -> WT[N][K] bf16 -----
__global__ __launch_bounds__(256) void transpose_w(
    const float* __restrict__ Wq, const float* __restrict__ Wk,
    const float* __restrict__ Wv, const float* __restrict__ Wo,
    const float* __restrict__ W1, const float* __restrict__ W2,
    int layer_base, unsigned short* __restrict__ wT) {
  int lz = blockIdx.x / 3072;
  int layer = layer_base + lz;
  int bid = blockIdx.x - lz * 3072;
  unsigned short* wTl = wT + (size_t)lz * 3145728;
  const float* src; unsigned short* dst; int R, Cn, tile, lg;
  if (bid < 1024) {
    int seg = bid >> 8; tile = bid & 255; R = 512; Cn = 512; lg = 4;
    const float* s4[4] = {Wq, Wk, Wv, Wo};
    src = s4[seg] + (size_t)layer * 262144;
    dst = wTl + (size_t)seg * 262144;
  } else if (bid < 2048) {
    tile = bid - 1024; R = 512; Cn = 2048; lg = 6;
    src = W1 + (size_t)layer * 1048576; dst = wTl + 1048576;
  } else {
    tile = bid - 2048; R = 2048; Cn = 512; lg = 4;
    src = W2 + (size_t)layer * 1048576; dst = wTl + 2097152;
  }
  int trb = tile >> lg, tcb = tile & ((1 << lg) - 1);
  __shared__ float tl[32][33];
  int t = threadIdx.x;
  int r = t >> 3, c4 = (t & 7) << 2;
  const float* sp = src + (size_t)(trb * 32 + r) * Cn + tcb * 32 + c4;
  float4 fv = *(const float4*)sp;
  tl[r][c4] = fv.x; tl[r][c4 + 1] = fv.y; tl[r][c4 + 2] = fv.z; tl[r][c4 + 3] = fv.w;
  __syncthreads();
  unsigned short* dp = dst + (size_t)(tcb * 32 + r) * R + trb * 32 + c4;
  ushort4 ov;
  ov.x = bfc(tl[c4][r]); ov.y = bfc(tl[c4 + 1][r]);
  ov.z = bfc(tl[c4 + 2][r]); ov.w = bfc(tl[c4 + 3][r]);
  *(ushort4*)dp = ov;
}

// ---------------- bf16 MFMA GEMM --------------------------------------------
// A bf16 [M][K], WT bf16 [N][K]; out = act(A@W + bias)(+res); BN=64, BK=64.
// BIAS2: cols >= 512 use bias2[col-512] (merged K|V projection).
template<int BM, int GELU, int RES, int OUTBF, int BIAS2>
__global__ __launch_bounds__(256) void gemm_bf(
    const unsigned short* __restrict__ A, const unsigned short* __restrict__ WT,
    const float* __restrict__ bias, const float* __restrict__ bias2,
    void* __restrict__ outp, const float* __restrict__ res, int M, int N, int K) {
  __shared__ unsigned short As[BM * 64];
  __shared__ unsigned short Bs[64 * 64];
  const int tid = threadIdx.x, lane = tid & 63, wid = tid >> 6;
  const int bm = blockIdx.y * BM, bn = blockIdx.x << 6;
  const int wm = (wid >> 1) * (BM / 2), wn = (wid & 1) << 5;
  constexpr int MF = BM / 32;
  f32x4 acc[MF][2] = {};
  const int fr = lane & 15, fq = lane >> 4;
  for (int k0 = 0; k0 < K; k0 += 64) {
    if (k0) __syncthreads();
    #pragma unroll
    for (int i = 0; i < BM / 32; i++) {
      int gl = tid + (i << 8);
      int row = gl >> 3, gc = gl & 7;
      short8v d = *(const short8v*)(A + (size_t)(bm + row) * K + k0 + (gc << 3));
      *(short8v*)((char*)As + ((((row << 7) + (gc << 4))) ^ ((row & 7) << 4))) = d;
    }
    #pragma unroll
    for (int i = 0; i < 2; i++) {
      int gl = tid + (i << 8);
      int row = gl >> 3, gc = gl & 7;
      short8v d = *(const short8v*)(WT + (size_t)(bn + row) * K + k0 + (gc << 3));
      *(short8v*)((char*)Bs + ((((row << 7) + (gc << 4))) ^ ((row & 7) << 4))) = d;
    }
    __syncthreads();
    short8v af[MF][2], bf2[2][2];
    #pragma unroll
    for (int mf = 0; mf < MF; mf++)
      #pragma unroll
      for (int ks = 0; ks < 2; ks++) {
        int r = wm + mf * 16 + fr;
        int c = (ks << 2) + fq;
        af[mf][ks] = *(const short8v*)((const char*)As + ((((r << 7) + (c << 4))) ^ ((r & 7) << 4)));
      }
    #pragma unroll
    for (int nf = 0; nf < 2; nf++)
      #pragma unroll
      for (int ks = 0; ks < 2; ks++) {
        int r = wn + nf * 16 + fr;
        int c = (ks << 2) + fq;
        bf2[nf][ks] = *(const short8v*)((const char*)Bs + ((((r << 7) + (c << 4))) ^ ((r & 7) << 4)));
      }
    #pragma unroll
    for (int mf = 0; mf < MF; mf++)
      #pragma unroll
      for (int nf = 0; nf < 2; nf++) {
        acc[mf][nf] = __builtin_amdgcn_mfma_f32_16x16x32_bf16(af[mf][0], bf2[nf][0], acc[mf][nf], 0, 0, 0);
        acc[mf][nf] = __builtin_amdgcn_mfma_f32_16x16x32_bf16(af[mf][1], bf2[nf][1], acc[mf][nf], 0, 0, 0);
      }
  }
  #pragma unroll
  for (int mf = 0; mf < MF; mf++)
    #pragma unroll
    for (int nf = 0; nf < 2; nf++) {
      int col = bn + wn + nf * 16 + fr;
      float bia = (BIAS2 && col >= 512) ? bias2[col - 512] : bias[col];
      #pragma unroll
      for (int rr = 0; rr < 4; rr++) {
        int row = bm + wm + mf * 16 + fq * 4 + rr;
        float vv = acc[mf][nf][rr] + bia;
        if (GELU) vv = 0.5f * vv * (1.0f + erff(vv * 0.70710678118654752f));
        if (RES)  vv += res[(size_t)row * N + col];
        if (OUTBF) ((unsigned short*)outp)[(size_t)row * N + col] = bfc(vv);
        else       ((float*)outp)[(size_t)row * N + col] = vv;
      }
    }
}

// ---------------- MFMA attention, 4 q-rows/block, 1 row/wave -----------------
// KV packed: row stride 1024 (K at h*64, V at 512+h*64). QK^T via MFMA (Q
// zero-padded to 16 rows); per-wave radix-select top-64 / softmax; PV gather.
template<int CAUSAL, int TOPK, int TSK>
__global__ __launch_bounds__(256, 5) void attn_m(
    const float* __restrict__ qf, const unsigned short* __restrict__ kv,
    unsigned short* __restrict__ yb) {
  constexpr int NT = TSK / 64;
  constexpr int NKC = TSK / 128;
  constexpr int SST = TSK + 8;
  __shared__ float S[4 * SST];
  __shared__ unsigned short Ks[128 * 64];  // 16KB, XOR-swizzled
  __shared__ unsigned short Qs[16 * 64];   // 2KB, XOR-swizzled (rows 4-15 zero)
  __shared__ float swt[TOPK ? 4 : 1][TOPK ? 128 : 1];
  __shared__ unsigned short kidx[TOPK ? 4 : 1][TOPK ? 128 : 1];
  int tid = threadIdx.x, lane = tid & 63, wid = tid >> 6;
  int bid = blockIdx.x;
  int swz = ((bid & 7) << 9) | (bid >> 3);  // 4096 blocks, bijective XCD swizzle
  int b = swz >> 9, h = (swz >> 6) & 7, qt = swz & 63;
  int q0 = qt << 2;
  // ---- stage Q (4 valid rows, pre-scaled by 1/8; rows 4-15 zero) ----
  {
    int row = tid >> 4, c4 = (tid & 15) << 2;
    ushort4 o;
    if (row < 4) {
      float4 qv = *(const float4*)(qf + (size_t)((b << 8) + q0 + row) * CC + (h << 6) + c4);
      o.x = bfc(qv.x * 0.125f); o.y = bfc(qv.y * 0.125f);
      o.z = bfc(qv.z * 0.125f); o.w = bfc(qv.w * 0.125f);
    } else {
      o.x = o.y = o.z = o.w = 0;
    }
    int off = (row << 7) + (c4 << 1);
    *(ushort4*)((char*)Qs + (off ^ ((row & 7) << 4))) = o;
  }
  __syncthreads();
  short8v aF[2];
  {
    int r = lane & 15, kq = lane >> 4;
    #pragma unroll
    for (int kc2 = 0; kc2 < 2; kc2++)
      aF[kc2] = *(const short8v*)((const char*)Qs +
                 (((r << 7) + (kc2 << 6) + (kq << 4)) ^ ((r & 7) << 4)));
  }
  int nte = NKC;
  if (CAUSAL) { int ub = (q0 + 4 + 127) >> 7; nte = ub < NKC ? ub : NKC; }
  const unsigned short* kgb = kv + (size_t)b * TSK * 1024 + (h << 6);
  for (int t = 0; t < nte; t++) {
    __syncthreads();
    {  // stage K tile: 128 keys x 64 dims bf16, swizzled
      int row = tid & 127, seg = tid >> 7;
      const unsigned short* src = kgb + (size_t)((t << 7) + row) * 1024 + (seg << 5);
      #pragma unroll
      for (int j = 0; j < 4; j++) {
        short8v d = *(const short8v*)(src + (j << 3));
        int slot = (seg << 2) + j;
        *(short8v*)((char*)Ks + (((row << 7) + (slot << 4)) ^ ((row & 7) << 4))) = d;
      }
    }
    __syncthreads();
    int kq = lane >> 4;
    #pragma unroll
    for (int f = 0; f < 2; f++) {
      f32x4 acc = {};
      int key16 = (wid << 5) + (f << 4) + (lane & 15);
      #pragma unroll
      for (int kc2 = 0; kc2 < 2; kc2++) {
        short8v bF = *(const short8v*)((const char*)Ks +
                      (((key16 << 7) + (kc2 << 6) + (kq << 4)) ^ ((key16 & 7) << 4)));
        acc = __builtin_amdgcn_mfma_f32_16x16x32_bf16(aF[kc2], bF, acc, 0, 0, 0);
      }
      if (kq == 0) {  // rows 0-3 live in fq==0 lanes
        int col = (t << 7) + key16;
        #pragma unroll
        for (int r = 0; r < 4; r++)
          S[r * SST + col] = acc[r];
      }
    }
  }
  __syncthreads();
  // ---- per-wave: one row select/softmax + PV gather ----
  int row = wid;
  int qi = q0 + row;
  int jmax = CAUSAL ? (qi + 1) : TSK;
  const unsigned short* vgb = kv + (size_t)b * TSK * 1024 + 512 + (h << 6) + lane;
  float sc[NT];
  float lmax = -3.0e38f;
  #pragma unroll
  for (int tt = 0; tt < NT; tt++) {
    int key = lane + (tt << 6);
    float v = (!CAUSAL || key < jmax) ? S[row * SST + key] : -3.0e38f;
    sc[tt] = v;
    lmax = fmaxf(lmax, v);
  }
  float mx = lmax;
  #pragma unroll
  for (int o = 32; o; o >>= 1) mx = fmaxf(mx, __shfl_xor(mx, o));
  float oacc = 0.f;
  if (TOPK) {
    unsigned key[NT];
    #pragma unroll
    for (int tt = 0; tt < NT; tt++) {
      unsigned u = __float_as_uint(sc[tt]);
      key[tt] = (u & 0x80000000u) ? ~u : (u | 0x80000000u);
    }
    unsigned prefix = 0u;
    #pragma unroll
    for (int bit = 31; bit >= 0; bit--) {
      unsigned cand = prefix | (1u << bit);
      int cnt = 0;
      #pragma unroll
      for (int tt = 0; tt < NT; tt++)
        cnt += __popcll(__ballot(key[tt] >= cand));
      if (cnt >= 64) prefix = cand;
    }
    float wvv[NT];
    float psum = 0.f;
    int basec = 0;
    #pragma unroll
    for (int tt = 0; tt < NT; tt++) {
      bool keep = key[tt] >= prefix;
      float wv = keep ? exp2f((sc[tt] - mx) * 1.4426950408889634f) : 0.f;
      wvv[tt] = wv;
      psum += wv;
      unsigned long long mask = __ballot(keep);
      if (keep) {
        int pos = basec + (int)__popcll(mask & ((1ull << lane) - 1ull));
        if (pos < 128) {
          kidx[row][pos] = (unsigned short)(lane + (tt << 6));
          swt[row][pos] = wv;
        }
      }
      basec += (int)__popcll(mask);
    }
    #pragma unroll
    for (int o = 32; o; o >>= 1) psum += __shfl_xor(psum, o);
    float inv = 1.0f / psum;
    int nk = basec;
    if (nk <= 128) {
      float a0 = 0.f, a1 = 0.f, a2 = 0.f, a3 = 0.f;
      int i = 0;
      for (; i + 3 < nk; i += 4) {
        a0 += swt[row][i]     * b2f(vgb[(size_t)kidx[row][i] * 1024]);
        a1 += swt[row][i + 1] * b2f(vgb[(size_t)kidx[row][i + 1] * 1024]);
        a2 += swt[row][i + 2] * b2f(vgb[(size_t)kidx[row][i + 2] * 1024]);
        a3 += swt[row][i + 3] * b2f(vgb[(size_t)kidx[row][i + 3] * 1024]);
      }
      for (; i < nk; i++) a0 += swt[row][i] * b2f(vgb[(size_t)kidx[row][i] * 1024]);
      oacc = (a0 + a1 + a2 + a3) * inv;
    } else {  // pathological tie overflow: full scan via S
      #pragma unroll
      for (int tt = 0; tt < NT; tt++)
        S[row * SST + lane + (tt << 6)] = wvv[tt];
      float a0 = 0.f, a1 = 0.f;
      for (int j = 0; j + 1 < TSK; j += 2) {
        a0 += S[row * SST + j]     * b2f(vgb[(size_t)j * 1024]);
        a1 += S[row * SST + j + 1] * b2f(vgb[(size_t)(j + 1) * 1024]);
      }
      oacc = (a0 + a1) * inv;
    }
  } else {
    float psum = 0.f;
    #pragma unroll
    for (int tt = 0; tt < NT; tt++) {
      int keyj = lane + (tt << 6);
      float wv = (keyj < jmax) ? exp2f((sc[tt] - mx) * 1.4426950408889634f) : 0.f;
      S[row * SST + keyj] = wv;
      psum += wv;
    }
    #pragma unroll
    for (int o = 32; o; o >>= 1) psum += __shfl_xor(psum, o);
    float inv = 1.0f / psum;
    float a0 = 0.f, a1 = 0.f, a2 = 0.f, a3 = 0.f;
    int j = 0;
    for (; j + 3 < jmax; j += 4) {
      a0 += S[row * SST + j]     * b2f(vgb[(size_t)j * 1024]);
      a1 += S[row * SST + j + 1] * b2f(vgb[(size_t)(j + 1) * 1024]);
      a2 += S[row * SST + j + 2] * b2f(vgb[(size_t)(j + 2) * 1024]);
      a3 += S[row * SST + j + 3] * b2f(vgb[(size_t)(j + 3) * 1024]);
    }
    for (; j < jmax; j++) a0 += S[row * SST + j] * b2f(vgb[(size_t)j * 1024]);
    oacc = (a0 + a1 + a2 + a3) * inv;
  }
  yb[(size_t)((b << 8) + qi) * CC + (h << 6) + lane] = bfc(oacc);
}

extern "C" void kernel_launch(void* const* d_in, const int* in_sizes, int n_in,
                              void* d_out, int out_size, void* d_ws, size_t ws_size,
                              hipStream_t stream) {
  const float* id_x    = (const float*)d_in[0];
  const float* id_prev = (const float*)d_in[1];
  const float* frames  = (const float*)d_in[2];
  const float* Wq = (const float*)d_in[3];  const float* bq = (const float*)d_in[4];
  const float* Wk = (const float*)d_in[5];  const float* bk = (const float*)d_in[6];
  const float* Wv = (const float*)d_in[7];  const float* bv = (const float*)d_in[8];
  const float* Wo = (const float*)d_in[9];  const float* bo = (const float*)d_in[10];
  const float* W1 = (const float*)d_in[11]; const float* b1 = (const float*)d_in[12];
  const float* W2 = (const float*)d_in[13]; const float* b2 = (const float*)d_in[14];
  const float* l1g = (const float*)d_in[15]; const float* l1b = (const float*)d_in[16];
  const float* l2g = (const float*)d_in[17]; const float* l2b = (const float*)d_in[18];
  const float* lfg = (const float*)d_in[19]; const float* lfb = (const float*)d_in[20];

  float* x = (float*)d_out;
  char* W  = (char*)d_ws;
  float*          qfb  = (float*)W;                                 // 4MB
  unsigned short* kvb  = (unsigned short*)(W + ((size_t)4  << 20)); // 8MB packed K|V
  unsigned short* m1b  = (unsigned short*)(W + ((size_t)4  << 20)); // 8MB, alias kv
  unsigned short* hb   = (unsigned short*)(W + ((size_t)12 << 20)); // 2MB
  unsigned short* ybf  = (unsigned short*)(W + ((size_t)14 << 20)); // 2MB
  unsigned short* xb   = (unsigned short*)(W + ((size_t)16 << 20)); // 2MB
  unsigned short* fb   = (unsigned short*)(W + ((size_t)18 << 20)); // 4MB
  unsigned short* pb   = (unsigned short*)(W + ((size_t)22 << 20)); // 2MB
  unsigned short* wT   = (unsigned short*)(W + ((size_t)24 << 20)); // 6MB or 60MB

  const bool allw = ws_size >= (((size_t)24 << 20) + (size_t)10 * 3145728 * 2);

  prep_k<<<4096, 256, 0, stream>>>(id_x, frames, id_prev, x, fb, pb);
  if (allw)
    transpose_w<<<30720, 256, 0, stream>>>(Wq, Wk, Wv, Wo, W1, W2, 0, wT);

  static const int ssrc[10] = {0, 0, 0, 0, 1, 1, 2, 2, 1, 1};

  for (int i = 0; i < 10; i++) {
    if (!allw)
      transpose_w<<<3072, 256, 0, stream>>>(Wq, Wk, Wv, Wo, W1, W2, i, wT);
    unsigned short* wTl = wT + (allw ? (size_t)i * 3145728 : 0);
    unsigned short* wqT = wTl;
    unsigned short* wkvT = wTl + 262144;   // [1024][512]: K rows then V rows
    unsigned short* woT = wTl + 786432;
    unsigned short* w1T = wTl + 1048576;
    unsigned short* w2T = wTl + 2097152;

    if (i == 0)
      ln_bf<<<2048, 256, 0, stream>>>(x, hb, l1g, l1b);

    // q = LN1(x) @ Wq + bq (fp32)
    gemm_bf<32, 0, 0, 0, 0><<<dim3(8, 64), 256, 0, stream>>>(hb, wqT, bq + i * 512, nullptr, qfb, nullptr, 2048, 512, 512);

    // kv = src @ [Wk|Wv] + [bk|bv]  (bf16, packed row stride 1024)
    const unsigned short* kvsrc; int Mkv;
    if (ssrc[i] == 0)      { kvsrc = fb; Mkv = 4096; }
    else if (ssrc[i] == 1) { kvsrc = xb; Mkv = 2048; }
    else                   { kvsrc = pb; Mkv = 2048; }
    if (Mkv == 4096)
      gemm_bf<64, 0, 0, 1, 1><<<dim3(16, 64), 256, 0, stream>>>(kvsrc, wkvT, bk + i * 512, bv + i * 512, kvb, nullptr, 4096, 1024, 512);
    else
      gemm_bf<32, 0, 0, 1, 1><<<dim3(16, 64), 256, 0, stream>>>(kvsrc, wkvT, bk + i * 512, bv + i * 512, kvb, nullptr, 2048, 1024, 512);

    if (ssrc[i] == 0)      attn_m<0, 1, 512><<<4096, 256, 0, stream>>>(qfb, kvb, ybf);
    else if (ssrc[i] == 1) attn_m<1, 0, 256><<<4096, 256, 0, stream>>>(qfb, kvb, ybf);
    else                   attn_m<0, 0, 256><<<4096, 256, 0, stream>>>(qfb, kvb, ybf);

    // x = x + y @ Wo + bo
    gemm_bf<32, 0, 1, 0, 0><<<dim3(8, 64), 256, 0, stream>>>(ybf, woT, bo + i * 512, nullptr, x, x, 2048, 512, 512);
    // h = LN2(x) bf16
    ln_bf<<<2048, 256, 0, stream>>>(x, hb, l2g + i * 512, l2b + i * 512);
    // m1 = gelu(h @ W1 + b1) bf16
    gemm_bf<64, 1, 0, 1, 0><<<dim3(32, 32), 256, 0, stream>>>(hb, w1T, b1 + i * 2048, nullptr, m1b, nullptr, 2048, 2048, 512);
    // x = x + m1 @ W2 + b2
    gemm_bf<32, 0, 1, 0, 0><<<dim3(8, 64), 256, 0, stream>>>(m1b, w2T, b2 + i * 512, nullptr, x, x, 2048, 512, 2048);

    if (i < 9)
      ln_chain<<<2048, 256, 0, stream>>>(x, x, xb, lfg + i * 512, lfb + i * 512,
                                         l1g + (i + 1) * 512, l1b + (i + 1) * 512, hb);
    else
      ln_final<<<2048, 256, 0, stream>>>(x, x, lfg + i * 512, lfb + i * 512);
  }
}

// Round 8
// 1005.903 us; speedup vs baseline: 6.7906x; 1.1799x over previous
//
#include <hip/hip_runtime.h>
#include <math.h>

#define CC 512
#define NH 8
#define HD 64
#define TT 256

typedef __attribute__((ext_vector_type(8))) short short8v;
typedef __attribute__((ext_vector_type(4))) float f32x4;

__device__ inline unsigned short bfc(float f) {  // fp32 -> bf16, RNE
  unsigned u = __float_as_uint(f);
  return (unsigned short)((u + 0x7fffu + ((u >> 16) & 1u)) >> 16);
}
__device__ inline float b2f(unsigned short s) {
  return __uint_as_float((unsigned)s << 16);
}
// async global->LDS, 16B per lane; l must be the wave-uniform base.
__device__ inline void gld16(const void* g, void* l) {
  __builtin_amdgcn_global_load_lds(
      (const __attribute__((address_space(1))) unsigned int*)g,
      (__attribute__((address_space(3))) unsigned int*)l, 16, 0, 0);
}

// ---------------- prep: x=id_x; fb=bf16(frames); pb=bf16(id_prev) ------------
__global__ __launch_bounds__(256) void prep_k(const float* __restrict__ id_x,
    const float* __restrict__ frames, const float* __restrict__ id_prev,
    float* __restrict__ x, unsigned short* __restrict__ fb,
    unsigned short* __restrict__ pb) {
  int i = blockIdx.x * 256 + threadIdx.x;  // 0..1048575
  if (i < 262144) {
    ((float4*)x)[i] = ((const float4*)id_x)[i];
  } else if (i < 786432) {
    int j = i - 262144;
    float4 f = ((const float4*)frames)[j];
    ushort4 o; o.x = bfc(f.x); o.y = bfc(f.y); o.z = bfc(f.z); o.w = bfc(f.w);
    ((ushort4*)fb)[j] = o;
  } else {
    int j = i - 786432;
    float4 f = ((const float4*)id_prev)[j];
    ushort4 o; o.x = bfc(f.x); o.y = bfc(f.y); o.z = bfc(f.z); o.w = bfc(f.w);
    ((ushort4*)pb)[j] = o;
  }
}

// ---------------- LayerNorm: one WAVE per row (no LDS, no barriers) ----------
__global__ __launch_bounds__(256) void ln_bf(const float* __restrict__ in,
    unsigned short* __restrict__ out, const float* __restrict__ g, const float* __restrict__ b) {
  int row = (blockIdx.x << 2) + (threadIdx.x >> 6), lane = threadIdx.x & 63;
  const float* r = in + (size_t)row * CC;
  float4 v0 = *(const float4*)(r + (lane << 2));
  float4 v1 = *(const float4*)(r + 256 + (lane << 2));
  float s = v0.x + v0.y + v0.z + v0.w + v1.x + v1.y + v1.z + v1.w;
  #pragma unroll
  for (int o = 32; o; o >>= 1) s += __shfl_xor(s, o);
  float mu = s * (1.0f / CC);
  float d0x = v0.x - mu, d0y = v0.y - mu, d0z = v0.z - mu, d0w = v0.w - mu;
  float d1x = v1.x - mu, d1y = v1.y - mu, d1z = v1.z - mu, d1w = v1.w - mu;
  float sq = d0x*d0x + d0y*d0y + d0z*d0z + d0w*d0w + d1x*d1x + d1y*d1y + d1z*d1z + d1w*d1w;
  #pragma unroll
  for (int o = 32; o; o >>= 1) sq += __shfl_xor(sq, o);
  float inv = rsqrtf(sq * (1.0f / CC) + 1e-5f);
  float4 g0 = *(const float4*)(g + (lane << 2)), g1 = *(const float4*)(g + 256 + (lane << 2));
  float4 b0 = *(const float4*)(b + (lane << 2)), b1 = *(const float4*)(b + 256 + (lane << 2));
  ushort4 o0, o1;
  o0.x = bfc(d0x*inv*g0.x + b0.x); o0.y = bfc(d0y*inv*g0.y + b0.y);
  o0.z = bfc(d0z*inv*g0.z + b0.z); o0.w = bfc(d0w*inv*g0.w + b0.w);
  o1.x = bfc(d1x*inv*g1.x + b1.x); o1.y = bfc(d1y*inv*g1.y + b1.y);
  o1.z = bfc(d1z*inv*g1.z + b1.z); o1.w = bfc(d1w*inv*g1.w + b1.w);
  *(ushort4*)(out + (size_t)row * CC + (lane << 2)) = o0;
  *(ushort4*)(out + (size_t)row * CC + 256 + (lane << 2)) = o1;
}

__global__ __launch_bounds__(256) void ln_final(const float* __restrict__ in,
    float* __restrict__ out, const float* __restrict__ g, const float* __restrict__ b) {
  int row = (blockIdx.x << 2) + (threadIdx.x >> 6), lane = threadIdx.x & 63;
  const float* r = in + (size_t)row * CC;
  float4 v0 = *(const float4*)(r + (lane << 2));
  float4 v1 = *(const float4*)(r + 256 + (lane << 2));
  float s = v0.x + v0.y + v0.z + v0.w + v1.x + v1.y + v1.z + v1.w;
  #pragma unroll
  for (int o = 32; o; o >>= 1) s += __shfl_xor(s, o);
  float mu = s * (1.0f / CC);
  float d0x = v0.x - mu, d0y = v0.y - mu, d0z = v0.z - mu, d0w = v0.w - mu;
  float d1x = v1.x - mu, d1y = v1.y - mu, d1z = v1.z - mu, d1w = v1.w - mu;
  float sq = d0x*d0x + d0y*d0y + d0z*d0z + d0w*d0w + d1x*d1x + d1y*d1y + d1z*d1z + d1w*d1w;
  #pragma unroll
  for (int o = 32; o; o >>= 1) sq += __shfl_xor(sq, o);
  float inv = rsqrtf(sq * (1.0f / CC) + 1e-5f);
  float4 g0 = *(const float4*)(g + (lane << 2)), g1 = *(const float4*)(g + 256 + (lane << 2));
  float4 b0 = *(const float4*)(b + (lane << 2)), b1 = *(const float4*)(b + 256 + (lane << 2));
  float4 o0, o1;
  o0.x = d0x*inv*g0.x + b0.x; o0.y = d0y*inv*g0.y + b0.y;
  o0.z = d0z*inv*g0.z + b0.z; o0.w = d0w*inv*g0.w + b0.w;
  o1.x = d1x*inv*g1.x + b1.x; o1.y = d1y*inv*g1.y + b1.y;
  o1.z = d1z*inv*g1.z + b1.z; o1.w = d1w*inv*g1.w + b1.w;
  *(float4*)(out + (size_t)row * CC + (lane << 2)) = o0;
  *(float4*)(out + (size_t)row * CC + 256 + (lane << 2)) = o1;
}

// LNf then LN1-of-next-layer: x fp32, xb bf16, h bf16 — all wave-local
__global__ __launch_bounds__(256) void ln_chain(const float* __restrict__ in,
    float* __restrict__ xout, unsigned short* __restrict__ xb,
    const float* __restrict__ gf, const float* __restrict__ bf,
    const float* __restrict__ g1, const float* __restrict__ b1,
    unsigned short* __restrict__ hout) {
  int row = (blockIdx.x << 2) + (threadIdx.x >> 6), lane = threadIdx.x & 63;
  const float* r = in + (size_t)row * CC;
  float4 v0 = *(const float4*)(r + (lane << 2));
  float4 v1 = *(const float4*)(r + 256 + (lane << 2));
  float s = v0.x + v0.y + v0.z + v0.w + v1.x + v1.y + v1.z + v1.w;
  #pragma unroll
  for (int o = 32; o; o >>= 1) s += __shfl_xor(s, o);
  float mu = s * (1.0f / CC);
  float d0x = v0.x - mu, d0y = v0.y - mu, d0z = v0.z - mu, d0w = v0.w - mu;
  float d1x = v1.x - mu, d1y = v1.y - mu, d1z = v1.z - mu, d1w = v1.w - mu;
  float sq = d0x*d0x + d0y*d0y + d0z*d0z + d0w*d0w + d1x*d1x + d1y*d1y + d1z*d1z + d1w*d1w;
  #pragma unroll
  for (int o = 32; o; o >>= 1) sq += __shfl_xor(sq, o);
  float inv = rsqrtf(sq * (1.0f / CC) + 1e-5f);
  float4 g0 = *(const float4*)(gf + (lane << 2)), g1v = *(const float4*)(gf + 256 + (lane << 2));
  float4 b0 = *(const float4*)(bf + (lane << 2)), b1v = *(const float4*)(bf + 256 + (lane << 2));
  float4 x0, x1;
  x0.x = d0x*inv*g0.x + b0.x; x0.y = d0y*inv*g0.y + b0.y;
  x0.z = d0z*inv*g0.z + b0.z; x0.w = d0w*inv*g0.w + b0.w;
  x1.x = d1x*inv*g1v.x + b1v.x; x1.y = d1y*inv*g1v.y + b1v.y;
  x1.z = d1z*inv*g1v.z + b1v.z; x1.w = d1w*inv*g1v.w + b1v.w;
  *(float4*)(xout + (size_t)row * CC + (lane << 2)) = x0;
  *(float4*)(xout + (size_t)row * CC + 256 + (lane << 2)) = x1;
  ushort4 xb0, xb1;
  xb0.x = bfc(x0.x); xb0.y = bfc(x0.y); xb0.z = bfc(x0.z); xb0.w = bfc(x0.w);
  xb1.x = bfc(x1.x); xb1.y = bfc(x1.y); xb1.z = bfc(x1.z); xb1.w = bfc(x1.w);
  *(ushort4*)(xb + (size_t)row * CC + (lane << 2)) = xb0;
  *(ushort4*)(xb + (size_t)row * CC + 256 + (lane << 2)) = xb1;
  // second LN
  float s2 = x0.x + x0.y + x0.z + x0.w + x1.x + x1.y + x1.z + x1.w;
  #pragma unroll
  for (int o = 32; o; o >>= 1) s2 += __shfl_xor(s2, o);
  float mu2 = s2 * (1.0f / CC);
  float e0x = x0.x - mu2, e0y = x0.y - mu2, e0z = x0.z - mu2, e0w = x0.w - mu2;
  float e1x = x1.x - mu2, e1y = x1.y - mu2, e1z = x1.z - mu2, e1w = x1.w - mu2;
  float sq2 = e0x*e0x + e0y*e0y + e0z*e0z + e0w*e0w + e1x*e1x + e1y*e1y + e1z*e1z + e1w*e1w;
  #pragma unroll
  for (int o = 32; o; o >>= 1) sq2 += __shfl_xor(sq2, o);
  float inv2 = rsqrtf(sq2 * (1.0f / CC) + 1e-5f);
  float4 h0 = *(const float4*)(g1 + (lane << 2)), h1 = *(const float4*)(g1 + 256 + (lane << 2));
  float4 c0 = *(const float4*)(b1 + (lane << 2)), c1 = *(const float4*)(b1 + 256 + (lane << 2));
  ushort4 ho0, ho1;
  ho0.x = bfc(e0x*inv2*h0.x + c0.x); ho0.y = bfc(e0y*inv2*h0.y + c0.y);
  ho0.z = bfc(e0z*inv2*h0.z + c0.z); ho0.w = bfc(e0w*inv2*h0.w + c0.w);
  ho1.x = bfc(e1x*inv2*h1.x + c1.x); ho1.y = bfc(e1y*inv2*h1.y + c1.y);
  ho1.z = bfc(e1z*inv2*h1.z + c1.z); ho1.w = bfc(e1w*inv2*h1.w + c1.w);
  *(ushort4*)(hout + (size_t)row * CC + (lane << 2)) = ho0;
  *(ushort4*)(hout + (size_t)row * CC + 256 + (lane << 2)) = ho1;
}

// ---------------- weight transpose+convert: W[K][N] fp32 -> WT[N][K] bf16 -----
__global__ __launch_bounds__(256) void transpose_w(
    const float* __restrict__ Wq, const float* __restrict__ Wk,
    const float* __restrict__ Wv, const float* __restrict__ Wo,
    const float* __restrict__ W1, const float* __restrict__ W2,
    int layer_base, unsigned short* __restrict__ wT) {
  int lz = blockIdx.x / 3072;
  int layer = layer_base + lz;
  int bid = blockIdx.x - lz * 3072;
  unsigned short* wTl = wT + (size_t)lz * 3145728;
  const float* src; unsigned short* dst; int R, Cn, tile, lg;
  if (bid < 1024) {
    int seg = bid >> 8; tile = bid & 255; R = 512; Cn = 512; lg = 4;
    const float* s4[4] = {Wq, Wk, Wv, Wo};
    src = s4[seg] + (size_t)layer * 262144;
    dst = wTl + (size_t)seg * 262144;
  } else if (bid < 2048) {
    tile = bid - 1024; R = 512; Cn = 2048; lg = 6;
    src = W1 + (size_t)layer * 1048576; dst = wTl + 1048576;
  } else {
    tile = bid - 2048; R = 2048; Cn = 512; lg = 4;
    src = W2 + (size_t)layer * 1048576; dst = wTl + 2097152;
  }
  int trb = tile >> lg, tcb = tile & ((1 << lg) - 1);
  __shared__ float tl[32][33];
  int t = threadIdx.x;
  int r = t >> 3, c4 = (t & 7) << 2;
  const float* sp = src + (size_t)(trb * 32 + r) * Cn + tcb * 32 + c4;
  float4 fv = *(const float4*)sp;
  tl[r][c4] = fv.x; tl[r][c4 + 1] = fv.y; tl[r][c4 + 2] = fv.z; tl[r][c4 + 3] = fv.w;
  __syncthreads();
  unsigned short* dp = dst + (size_t)(tcb * 32 + r) * R + trb * 32 + c4;
  ushort4 ov;
  ov.x = bfc(tl[c4][r]); ov.y = bfc(tl[c4 + 1][r]);
  ov.z = bfc(tl[c4 + 2][r]); ov.w = bfc(tl[c4 + 3][r]);
  *(ushort4*)dp = ov;
}

// ---------------- bf16 MFMA GEMM with global_load_lds staging ----------------
// A bf16 [M][K], WT bf16 [N][K]; out = act(A@W + bias)(+res); BN=64, BK=64.
// Linear LDS dest + inverse-XOR-swizzled global source (both-sides rule).
template<int BM, int GELU, int RES, int OUTBF, int BIAS2>
__global__ __launch_bounds__(256) void gemm_bf(
    const unsigned short* __restrict__ A, const unsigned short* __restrict__ WT,
    const float* __restrict__ bias, const float* __restrict__ bias2,
    void* __restrict__ outp, const float* __restrict__ res, int M, int N, int K) {
  __shared__ __align__(16) unsigned short As[BM * 64];
  __shared__ __align__(16) unsigned short Bs[64 * 64];
  const int tid = threadIdx.x, lane = tid & 63, wid = tid >> 6;
  const int bm = blockIdx.y * BM, bn = blockIdx.x << 6;
  const int wm = (wid >> 1) * (BM / 2), wn = (wid & 1) << 5;
  constexpr int MF = BM / 32;
  f32x4 acc[MF][2] = {};
  const int fr = lane & 15, fq = lane >> 4;
  // per-lane staging source coords (linear LDS slot = gl, source col gc^(row&7))
  for (int k0 = 0; k0 < K; k0 += 64) {
    if (k0) __syncthreads();
    #pragma unroll
    for (int i = 0; i < BM / 32; i++) {
      int gl = tid + (i << 8);
      int row = gl >> 3, gc = gl & 7;
      int gcs = gc ^ (row & 7);
      gld16(A + (size_t)(bm + row) * K + k0 + (gcs << 3),
            (char*)As + (i << 12) + (wid << 10));
    }
    #pragma unroll
    for (int i = 0; i < 2; i++) {
      int gl = tid + (i << 8);
      int row = gl >> 3, gc = gl & 7;
      int gcs = gc ^ (row & 7);
      gld16(WT + (size_t)(bn + row) * K + k0 + (gcs << 3),
            (char*)Bs + (i << 12) + (wid << 10));
    }
    __syncthreads();
    short8v af[MF][2], bf2[2][2];
    #pragma unroll
    for (int mf = 0; mf < MF; mf++)
      #pragma unroll
      for (int ks = 0; ks < 2; ks++) {
        int r = wm + mf * 16 + fr;
        int c = (ks << 2) + fq;
        af[mf][ks] = *(const short8v*)((const char*)As + ((((r << 7) + (c << 4))) ^ ((r & 7) << 4)));
      }
    #pragma unroll
    for (int nf = 0; nf < 2; nf++)
      #pragma unroll
      for (int ks = 0; ks < 2; ks++) {
        int r = wn + nf * 16 + fr;
        int c = (ks << 2) + fq;
        bf2[nf][ks] = *(const short8v*)((const char*)Bs + ((((r << 7) + (c << 4))) ^ ((r & 7) << 4)));
      }
    #pragma unroll
    for (int mf = 0; mf < MF; mf++)
      #pragma unroll
      for (int nf = 0; nf < 2; nf++) {
        acc[mf][nf] = __builtin_amdgcn_mfma_f32_16x16x32_bf16(af[mf][0], bf2[nf][0], acc[mf][nf], 0, 0, 0);
        acc[mf][nf] = __builtin_amdgcn_mfma_f32_16x16x32_bf16(af[mf][1], bf2[nf][1], acc[mf][nf], 0, 0, 0);
      }
  }
  #pragma unroll
  for (int mf = 0; mf < MF; mf++)
    #pragma unroll
    for (int nf = 0; nf < 2; nf++) {
      int col = bn + wn + nf * 16 + fr;
      float bia = (BIAS2 && col >= 512) ? bias2[col - 512] : bias[col];
      #pragma unroll
      for (int rr = 0; rr < 4; rr++) {
        int row = bm + wm + mf * 16 + fq * 4 + rr;
        float vv = acc[mf][nf][rr] + bia;
        if (GELU) vv = 0.5f * vv * (1.0f + erff(vv * 0.70710678118654752f));
        if (RES)  vv += res[(size_t)row * N + col];
        if (OUTBF) ((unsigned short*)outp)[(size_t)row * N + col] = bfc(vv);
        else       ((float*)outp)[(size_t)row * N + col] = vv;
      }
    }
}

// ---------------- MFMA attention: 8 q-rows/block, 8 waves, 1 row/wave --------
// KV packed row stride 1024 (K at h*64, V at 512+h*64). K staged via
// global_load_lds (pre-swizzled source). Early-exit radix select.
template<int CAUSAL, int TOPK, int TSK>
__global__ __launch_bounds__(512, 4) void attn_m(
    const unsigned short* __restrict__ qb, const unsigned short* __restrict__ kv,
    unsigned short* __restrict__ yb) {
  constexpr int NT = TSK / 64;
  constexpr int NKC = TSK / 128;
  constexpr int SST = TSK + 8;
  __shared__ float S[8 * SST];
  __shared__ __align__(16) unsigned short Ks[128 * 64];  // 16KB
  __shared__ __align__(16) unsigned short Qs[16 * 64];   // 2KB (rows 8-15 zero)
  __shared__ float swt[TOPK ? 8 : 1][TOPK ? 128 : 1];
  __shared__ unsigned short kidx[TOPK ? 8 : 1][TOPK ? 128 : 1];
  int tid = threadIdx.x, lane = tid & 63, wid = tid >> 6;
  int bid = blockIdx.x;
  int swz = ((bid & 7) << 8) | (bid >> 3);  // 2048 blocks, bijective XCD swizzle
  int b = swz >> 8, h = (swz >> 5) & 7, q0 = (swz & 31) << 3;
  // ---- stage Q: 16 rows x 8 slots, rows 0-7 valid (scaled 1/8), 8-15 zero ----
  if (tid < 128) {
    int row = tid >> 3, gc = tid & 7;
    short8v o8 = {0, 0, 0, 0, 0, 0, 0, 0};
    if (row < 8) {
      const unsigned short* qsrc = qb + (size_t)((b << 8) + q0 + row) * CC + (h << 6) + (gc << 3);
      short8v raw = *(const short8v*)qsrc;
      #pragma unroll
      for (int e = 0; e < 8; e++)
        o8[e] = (short)bfc(b2f((unsigned short)raw[e]) * 0.125f);
    }
    *(short8v*)((char*)Qs + ((tid << 4) ^ ((row & 7) << 4))) = o8;
  }
  __syncthreads();
  short8v aF[2];
  {
    int r = lane & 15, kq2 = lane >> 4;
    #pragma unroll
    for (int kc2 = 0; kc2 < 2; kc2++)
      aF[kc2] = *(const short8v*)((const char*)Qs +
                 (((r << 7) + (kc2 << 6) + (kq2 << 4)) ^ ((r & 7) << 4)));
  }
  int nte = NKC;
  if (CAUSAL) { int ub = (q0 + 8 + 127) >> 7; nte = ub < NKC ? ub : NKC; }
  const unsigned short* kgb = kv + (size_t)b * TSK * 1024 + (h << 6);
  for (int t = 0; t < nte; t++) {
    __syncthreads();
    #pragma unroll
    for (int j = 0; j < 2; j++) {  // stage 128x64 bf16 K tile, swizzled source
      int s = (wid << 7) + (j << 6) + lane;
      int row = s >> 3, sp = s & 7;
      gld16(kgb + (size_t)((t << 7) + row) * 1024 + ((sp ^ (row & 7)) << 3),
            (char*)Ks + (wid << 11) + (j << 10));
    }
    __syncthreads();
    int kq2 = lane >> 4;
    f32x4 acc = {};
    int key16 = (wid << 4) + (lane & 15);
    #pragma unroll
    for (int kc2 = 0; kc2 < 2; kc2++) {
      short8v bF = *(const short8v*)((const char*)Ks +
                    (((key16 << 7) + (kc2 << 6) + (kq2 << 4)) ^ ((key16 & 7) << 4)));
      acc = __builtin_amdgcn_mfma_f32_16x16x32_bf16(aF[kc2], bF, acc, 0, 0, 0);
    }
    if (kq2 < 2) {  // rows 0-7 live in fq 0,1
      int col = (t << 7) + key16;
      #pragma unroll
      for (int r = 0; r < 4; r++)
        S[(kq2 * 4 + r) * SST + col] = acc[r];
    }
  }
  __syncthreads();
  // ---- per-wave: one row select/softmax + PV gather ----
  int row = wid;
  int qi = q0 + row;
  int jmax = CAUSAL ? (qi + 1) : TSK;
  const unsigned short* vgb = kv + (size_t)b * TSK * 1024 + 512 + (h << 6) + lane;
  float sc[NT];
  float lmax = -3.0e38f;
  #pragma unroll
  for (int tt = 0; tt < NT; tt++) {
    int key = lane + (tt << 6);
    float v = (!CAUSAL || key < jmax) ? S[row * SST + key] : -3.0e38f;
    sc[tt] = v;
    lmax = fmaxf(lmax, v);
  }
  float mx = lmax;
  #pragma unroll
  for (int o = 32; o; o >>= 1) mx = fmaxf(mx, __shfl_xor(mx, o));
  float oacc = 0.f;
  if (TOPK) {
    unsigned key[NT];
    #pragma unroll
    for (int tt = 0; tt < NT; tt++) {
      unsigned u = __float_as_uint(sc[tt]);
      key[tt] = (u & 0x80000000u) ? ~u : (u | 0x80000000u);
    }
    unsigned prefix = 0u;
    for (int bit = 31; bit >= 0; bit--) {   // early exit when kept set exact
      unsigned cand = prefix | (1u << bit);
      int cnt = 0;
      #pragma unroll
      for (int tt = 0; tt < NT; tt++)
        cnt += __popcll(__ballot(key[tt] >= cand));
      if (cnt >= 64) {
        prefix = cand;
        if (cnt == 64) break;
      }
    }
    float wvv[NT];
    float psum = 0.f;
    int basec = 0;
    #pragma unroll
    for (int tt = 0; tt < NT; tt++) {
      bool keep = key[tt] >= prefix;
      float wv = keep ? exp2f((sc[tt] - mx) * 1.4426950408889634f) : 0.f;
      wvv[tt] = wv;
      psum += wv;
      unsigned long long mask = __ballot(keep);
      if (keep) {
        int pos = basec + (int)__popcll(mask & ((1ull << lane) - 1ull));
        if (pos < 128) {
          kidx[row][pos] = (unsigned short)(lane + (tt << 6));
          swt[row][pos] = wv;
        }
      }
      basec += (int)__popcll(mask);
    }
    #pragma unroll
    for (int o = 32; o; o >>= 1) psum += __shfl_xor(psum, o);
    float inv = 1.0f / psum;
    int nk = basec;
    if (nk <= 128) {
      float a0 = 0.f, a1 = 0.f, a2 = 0.f, a3 = 0.f;
      int i = 0;
      for (; i + 3 < nk; i += 4) {
        a0 += swt[row][i]     * b2f(vgb[(size_t)kidx[row][i] * 1024]);
        a1 += swt[row][i + 1] * b2f(vgb[(size_t)kidx[row][i + 1] * 1024]);
        a2 += swt[row][i + 2] * b2f(vgb[(size_t)kidx[row][i + 2] * 1024]);
        a3 += swt[row][i + 3] * b2f(vgb[(size_t)kidx[row][i + 3] * 1024]);
      }
      for (; i < nk; i++) a0 += swt[row][i] * b2f(vgb[(size_t)kidx[row][i] * 1024]);
      oacc = (a0 + a1 + a2 + a3) * inv;
    } else {  // pathological tie overflow: full scan via S
      #pragma unroll
      for (int tt = 0; tt < NT; tt++)
        S[row * SST + lane + (tt << 6)] = wvv[tt];
      float a0 = 0.f, a1 = 0.f;
      for (int j = 0; j + 1 < TSK; j += 2) {
        a0 += S[row * SST + j]     * b2f(vgb[(size_t)j * 1024]);
        a1 += S[row * SST + j + 1] * b2f(vgb[(size_t)(j + 1) * 1024]);
      }
      oacc = (a0 + a1) * inv;
    }
  } else {
    float psum = 0.f;
    #pragma unroll
    for (int tt = 0; tt < NT; tt++) {
      int keyj = lane + (tt << 6);
      float wv = (keyj < jmax) ? exp2f((sc[tt] - mx) * 1.4426950408889634f) : 0.f;
      S[row * SST + keyj] = wv;
      psum += wv;
    }
    #pragma unroll
    for (int o = 32; o; o >>= 1) psum += __shfl_xor(psum, o);
    float inv = 1.0f / psum;
    float a0 = 0.f, a1 = 0.f, a2 = 0.f, a3 = 0.f;
    int j = 0;
    for (; j + 3 < jmax; j += 4) {
      a0 += S[row * SST + j]     * b2f(vgb[(size_t)j * 1024]);
      a1 += S[row * SST + j + 1] * b2f(vgb[(size_t)(j + 1) * 1024]);
      a2 += S[row * SST + j + 2] * b2f(vgb[(size_t)(j + 2) * 1024]);
      a3 += S[row * SST + j + 3] * b2f(vgb[(size_t)(j + 3) * 1024]);
    }
    for (; j < jmax; j++) a0 += S[row * SST + j] * b2f(vgb[(size_t)j * 1024]);
    oacc = (a0 + a1 + a2 + a3) * inv;
  }
  yb[(size_t)((b << 8) + qi) * CC + (h << 6) + lane] = bfc(oacc);
}

extern "C" void kernel_launch(void* const* d_in, const int* in_sizes, int n_in,
                              void* d_out, int out_size, void* d_ws, size_t ws_size,
                              hipStream_t stream) {
  const float* id_x    = (const float*)d_in[0];
  const float* id_prev = (const float*)d_in[1];
  const float* frames  = (const float*)d_in[2];
  const float* Wq = (const float*)d_in[3];  const float* bq = (const float*)d_in[4];
  const float* Wk = (const float*)d_in[5];  const float* bk = (const float*)d_in[6];
  const float* Wv = (const float*)d_in[7];  const float* bv = (const float*)d_in[8];
  const float* Wo = (const float*)d_in[9];  const float* bo = (const float*)d_in[10];
  const float* W1 = (const float*)d_in[11]; const float* b1 = (const float*)d_in[12];
  const float* W2 = (const float*)d_in[13]; const float* b2 = (const float*)d_in[14];
  const float* l1g = (const float*)d_in[15]; const float* l1b = (const float*)d_in[16];
  const float* l2g = (const float*)d_in[17]; const float* l2b = (const float*)d_in[18];
  const float* lfg = (const float*)d_in[19]; const float* lfb = (const float*)d_in[20];

  float* x = (float*)d_out;
  char* W  = (char*)d_ws;
  unsigned short* qbuf = (unsigned short*)W;                        // 2MB bf16 q
  unsigned short* kvb  = (unsigned short*)(W + ((size_t)4  << 20)); // 8MB packed K|V
  unsigned short* m1b  = (unsigned short*)(W + ((size_t)4  << 20)); // 8MB, alias kv
  unsigned short* hb   = (unsigned short*)(W + ((size_t)12 << 20)); // 2MB
  unsigned short* ybf  = (unsigned short*)(W + ((size_t)14 << 20)); // 2MB
  unsigned short* xb   = (unsigned short*)(W + ((size_t)16 << 20)); // 2MB
  unsigned short* fb   = (unsigned short*)(W + ((size_t)18 << 20)); // 4MB
  unsigned short* pb   = (unsigned short*)(W + ((size_t)22 << 20)); // 2MB
  unsigned short* wT   = (unsigned short*)(W + ((size_t)24 << 20)); // 6MB or 60MB

  const bool allw = ws_size >= (((size_t)24 << 20) + (size_t)10 * 3145728 * 2);

  prep_k<<<4096, 256, 0, stream>>>(id_x, frames, id_prev, x, fb, pb);
  if (allw)
    transpose_w<<<30720, 256, 0, stream>>>(Wq, Wk, Wv, Wo, W1, W2, 0, wT);

  static const int ssrc[10] = {0, 0, 0, 0, 1, 1, 2, 2, 1, 1};

  for (int i = 0; i < 10; i++) {
    if (!allw)
      transpose_w<<<3072, 256, 0, stream>>>(Wq, Wk, Wv, Wo, W1, W2, i, wT);
    unsigned short* wTl = wT + (allw ? (size_t)i * 3145728 : 0);
    unsigned short* wqT = wTl;
    unsigned short* wkvT = wTl + 262144;   // [1024][512]: K rows then V rows
    unsigned short* woT = wTl + 786432;
    unsigned short* w1T = wTl + 1048576;
    unsigned short* w2T = wTl + 2097152;

    if (i == 0)
      ln_bf<<<512, 256, 0, stream>>>(x, hb, l1g, l1b);

    // q = LN1(x) @ Wq + bq (bf16)
    gemm_bf<32, 0, 0, 1, 0><<<dim3(8, 64), 256, 0, stream>>>(hb, wqT, bq + i * 512, nullptr, qbuf, nullptr, 2048, 512, 512);

    // kv = src @ [Wk|Wv] + [bk|bv]  (bf16, packed row stride 1024)
    const unsigned short* kvsrc; int Mkv;
    if (ssrc[i] == 0)      { kvsrc = fb; Mkv = 4096; }
    else if (ssrc[i] == 1) { kvsrc = xb; Mkv = 2048; }
    else                   { kvsrc = pb; Mkv = 2048; }
    if (Mkv == 4096)
      gemm_bf<64, 0, 0, 1, 1><<<dim3(16, 64), 256, 0, stream>>>(kvsrc, wkvT, bk + i * 512, bv + i * 512, kvb, nullptr, 4096, 1024, 512);
    else
      gemm_bf<32, 0, 0, 1, 1><<<dim3(16, 64), 256, 0, stream>>>(kvsrc, wkvT, bk + i * 512, bv + i * 512, kvb, nullptr, 2048, 1024, 512);

    if (ssrc[i] == 0)      attn_m<0, 1, 512><<<2048, 512, 0, stream>>>(qbuf, kvb, ybf);
    else if (ssrc[i] == 1) attn_m<1, 0, 256><<<2048, 512, 0, stream>>>(qbuf, kvb, ybf);
    else                   attn_m<0, 0, 256><<<2048, 512, 0, stream>>>(qbuf, kvb, ybf);

    // x = x + y @ Wo + bo
    gemm_bf<32, 0, 1, 0, 0><<<dim3(8, 64), 256, 0, stream>>>(ybf, woT, bo + i * 512, nullptr, x, x, 2048, 512, 512);
    // h = LN2(x) bf16
    ln_bf<<<512, 256, 0, stream>>>(x, hb, l2g + i * 512, l2b + i * 512);
    // m1 = gelu(h @ W1 + b1) bf16
    gemm_bf<64, 1, 0, 1, 0><<<dim3(32, 32), 256, 0, stream>>>(hb, w1T, b1 + i * 2048, nullptr, m1b, nullptr, 2048, 2048, 512);
    // x = x + m1 @ W2 + b2
    gemm_bf<32, 0, 1, 0, 0><<<dim3(8, 64), 256, 0, stream>>>(m1b, w2T, b2 + i * 512, nullptr, x, x, 2048, 512, 2048);

    if (i < 9)
      ln_chain<<<512, 256, 0, stream>>>(x, x, xb, lfg + i * 512, lfb + i * 512,
                                        l1g + (i + 1) * 512, l1b + (i + 1) * 512, hb);
    else
      ln_final<<<512, 256, 0, stream>>>(x, x, lfg + i * 512, lfb + i * 512);
  }
}